// Round 1
// baseline (4801.324 us; speedup 1.0000x reference)
//
#include <hip/hip_runtime.h>

#define HID 64

// ---------------------------------------------------------------------------
// Edge message kernel: m = relu([Hn[src], Xe] @ W + b); agg[dst] += m
// Tiled GEMM: 64 edges x 64 channels per block tile, K = K1+K2 (48 or 80).
// 256 threads, each computes a 4x4 micro-tile (4 edges x 4 channels).
// ---------------------------------------------------------------------------
template<int K1, int K2>
__global__ __launch_bounds__(256) void edge_msg(
    const float* __restrict__ Hn,    // [N, K1] node features
    const float* __restrict__ Xe,    // [E, K2] edge features
    const int*   __restrict__ src,
    const int*   __restrict__ dst,
    const float* __restrict__ W,     // [K1+K2, 64]
    const float* __restrict__ bias,  // [64]
    float*       __restrict__ agg,   // [N, 64] (pre-zeroed)
    int E)
{
    constexpr int K  = K1 + K2;
    constexpr int KP = K + 4;                 // pad to dodge staging-write bank conflicts
    __shared__ float Ws[K * HID];             // 12.3 KB (K=48) / 20.5 KB (K=80)
    __shared__ float Xs[64 * KP];             // 13.3 KB / 21.5 KB

    const int tid = threadIdx.x;

    // stage W once per block (exact multiple: K*HID/1024 float4 per thread)
    for (int i = tid * 4; i < K * HID; i += 256 * 4)
        *(float4*)&Ws[i] = *(const float4*)&W[i];

    const int c0  = (tid & 15) * 4;           // channel group
    const int e0l = (tid >> 4) * 4;           // local edge group
    const float4 bvec = *(const float4*)&bias[c0];

    const int ntiles = (E + 63) / 64;
    for (int tile = blockIdx.x; tile < ntiles; tile += gridDim.x) {
        const int ebase = tile * 64;
        __syncthreads();                      // protect Xs (also covers Ws on first iter)
        // ---- stage X tile: 4 threads per edge gather [h[src] ; xe] ----
        {
            const int el = tid >> 2;
            const int p  = tid & 3;
            const int e  = ebase + el;
            if (e < E) {
                const int s = src[e];
                const float* hrow = Hn + (size_t)s * K1;
                const float* xrow = Xe + (size_t)e * K2;
                #pragma unroll
                for (int i = p; i < K / 4; i += 4) {
                    const int k = i * 4;
                    float4 v = (k < K1) ? *(const float4*)&hrow[k]
                                        : *(const float4*)&xrow[k - K1];
                    *(float4*)&Xs[el * KP + k] = v;
                }
            }
        }
        __syncthreads();

        float acc[4][4];
        #pragma unroll
        for (int i = 0; i < 4; i++)
            #pragma unroll
            for (int j = 0; j < 4; j++) acc[i][j] = 0.f;

        #pragma unroll 4
        for (int k = 0; k < K; k += 4) {
            const float4 w0 = *(const float4*)&Ws[(k + 0) * HID + c0];
            const float4 w1 = *(const float4*)&Ws[(k + 1) * HID + c0];
            const float4 w2 = *(const float4*)&Ws[(k + 2) * HID + c0];
            const float4 w3 = *(const float4*)&Ws[(k + 3) * HID + c0];
            #pragma unroll
            for (int ei = 0; ei < 4; ei++) {
                const float4 xv = *(const float4*)&Xs[(e0l + ei) * KP + k];
                acc[ei][0] += xv.x * w0.x + xv.y * w1.x + xv.z * w2.x + xv.w * w3.x;
                acc[ei][1] += xv.x * w0.y + xv.y * w1.y + xv.z * w2.y + xv.w * w3.y;
                acc[ei][2] += xv.x * w0.z + xv.y * w1.z + xv.z * w2.z + xv.w * w3.z;
                acc[ei][3] += xv.x * w0.w + xv.y * w1.w + xv.z * w2.w + xv.w * w3.w;
            }
        }

        // ---- bias + relu + atomic scatter ----
        #pragma unroll
        for (int ei = 0; ei < 4; ei++) {
            const int e = ebase + e0l + ei;
            if (e < E) {
                float* arow = agg + (size_t)dst[e] * HID + c0;
                atomicAdd(arow + 0, fmaxf(acc[ei][0] + bvec.x, 0.f));
                atomicAdd(arow + 1, fmaxf(acc[ei][1] + bvec.y, 0.f));
                atomicAdd(arow + 2, fmaxf(acc[ei][2] + bvec.z, 0.f));
                atomicAdd(arow + 3, fmaxf(acc[ei][3] + bvec.w, 0.f));
            }
        }
    }
}

// ---------------------------------------------------------------------------
// Node update: y = relu([Hn, Agg] @ W + b). 32 nodes x 64 ch per tile,
// 2x4 micro-tiles. Yout may alias Hn (rows are tile-exclusive).
// ---------------------------------------------------------------------------
template<int K1>
__global__ __launch_bounds__(256) void node_update(
    const float* __restrict__ Hn,    // [N, K1]
    const float* __restrict__ Agg,   // [N, 64]
    const float* __restrict__ W,     // [K1+64, 64]
    const float* __restrict__ bias,  // [64]
    float*       __restrict__ Yout,  // [N, 64]
    int N)
{
    constexpr int K  = K1 + HID;              // 96 or 128
    constexpr int KP = K + 4;
    __shared__ float Ws[K * HID];             // 24.6 / 32.8 KB
    __shared__ float Xs[32 * KP];             // 12.8 / 16.9 KB

    const int tid = threadIdx.x;
    for (int i = tid * 4; i < K * HID; i += 256 * 4)
        *(float4*)&Ws[i] = *(const float4*)&W[i];

    const int c0  = (tid & 15) * 4;
    const int n0l = (tid >> 4) * 2;
    const float4 bvec = *(const float4*)&bias[c0];

    const int ntiles = (N + 31) / 32;
    for (int tile = blockIdx.x; tile < ntiles; tile += gridDim.x) {
        const int nbase = tile * 32;
        __syncthreads();
        {
            const int nl = tid >> 3;          // 8 threads per node
            const int p  = tid & 7;
            const int n  = nbase + nl;
            if (n < N) {
                const float* hrow = Hn  + (size_t)n * K1;
                const float* arow = Agg + (size_t)n * HID;
                #pragma unroll
                for (int i = p; i < K / 4; i += 8) {
                    const int k = i * 4;
                    float4 v = (k < K1) ? *(const float4*)&hrow[k]
                                        : *(const float4*)&arow[k - K1];
                    *(float4*)&Xs[nl * KP + k] = v;
                }
            }
        }
        __syncthreads();

        float acc[2][4];
        #pragma unroll
        for (int i = 0; i < 2; i++)
            #pragma unroll
            for (int j = 0; j < 4; j++) acc[i][j] = 0.f;

        #pragma unroll 4
        for (int k = 0; k < K; k += 4) {
            const float4 w0 = *(const float4*)&Ws[(k + 0) * HID + c0];
            const float4 w1 = *(const float4*)&Ws[(k + 1) * HID + c0];
            const float4 w2 = *(const float4*)&Ws[(k + 2) * HID + c0];
            const float4 w3 = *(const float4*)&Ws[(k + 3) * HID + c0];
            #pragma unroll
            for (int ni = 0; ni < 2; ni++) {
                const float4 xv = *(const float4*)&Xs[(n0l + ni) * KP + k];
                acc[ni][0] += xv.x * w0.x + xv.y * w1.x + xv.z * w2.x + xv.w * w3.x;
                acc[ni][1] += xv.x * w0.y + xv.y * w1.y + xv.z * w2.y + xv.w * w3.y;
                acc[ni][2] += xv.x * w0.z + xv.y * w1.z + xv.z * w2.z + xv.w * w3.z;
                acc[ni][3] += xv.x * w0.w + xv.y * w1.w + xv.z * w2.w + xv.w * w3.w;
            }
        }

        #pragma unroll
        for (int ni = 0; ni < 2; ni++) {
            const int n = nbase + n0l + ni;
            if (n < N) {
                float4 o;
                o.x = fmaxf(acc[ni][0] + bvec.x, 0.f);
                o.y = fmaxf(acc[ni][1] + bvec.y, 0.f);
                o.z = fmaxf(acc[ni][2] + bvec.z, 0.f);
                o.w = fmaxf(acc[ni][3] + bvec.w, 0.f);
                *(float4*)&Yout[(size_t)n * HID + c0] = o;
            }
        }
    }
}

// ---------------------------------------------------------------------------
// Pooling: pool[batch_idx[n]] += y[n]
// ---------------------------------------------------------------------------
__global__ __launch_bounds__(256) void pool_kernel(
    const float* __restrict__ Y, const int* __restrict__ bidx,
    float* __restrict__ pool, int N)
{
    const int idx = blockIdx.x * blockDim.x + threadIdx.x;
    if (idx >= N * 16) return;
    const int n = idx >> 4, c4 = idx & 15;
    const float4 v = *(const float4*)&Y[(size_t)n * HID + c4 * 4];
    float* p = pool + (size_t)bidx[n] * HID + c4 * 4;
    atomicAdd(p + 0, v.x); atomicAdd(p + 1, v.y);
    atomicAdd(p + 2, v.z); atomicAdd(p + 3, v.w);
}

// ---------------------------------------------------------------------------
// Head: out[g] = pool[g] . Ww + Wb   (one wave per graph)
// ---------------------------------------------------------------------------
__global__ __launch_bounds__(256) void head_kernel(
    const float* __restrict__ pool, const float* __restrict__ Ww,
    const float* __restrict__ Wb, float* __restrict__ out)
{
    const int g    = blockIdx.x * 4 + (threadIdx.x >> 6);
    const int lane = threadIdx.x & 63;
    float v = pool[g * HID + lane] * Ww[lane];
    #pragma unroll
    for (int off = 32; off; off >>= 1) v += __shfl_down(v, off);
    if (lane == 0) out[g] = v + Wb[0];
}

extern "C" void kernel_launch(void* const* d_in, const int* in_sizes, int n_in,
                              void* d_out, int out_size, void* d_ws, size_t ws_size,
                              hipStream_t stream) {
    const float* H    = (const float*)d_in[0];
    const float* Xe   = (const float*)d_in[1];
    const int*   ids  = (const int*)d_in[2];   // [2, E]
    const int*   bidx = (const int*)d_in[3];   // [N]
    const float* Mw0  = (const float*)d_in[4];
    const float* Mb0  = (const float*)d_in[5];
    const float* Uw0  = (const float*)d_in[6];
    const float* Ub0  = (const float*)d_in[7];
    const float* MwH  = (const float*)d_in[8];  // [3, 80, 64]
    const float* MbH  = (const float*)d_in[9];  // [3, 64]
    const float* UwH  = (const float*)d_in[10]; // [3, 128, 64]
    const float* UbH  = (const float*)d_in[11]; // [3, 64]
    const float* Ww   = (const float*)d_in[12]; // [64]
    const float* Wb   = (const float*)d_in[13]; // [1]
    float* out = (float*)d_out;

    const int N = in_sizes[0] / 32;
    const int E = in_sizes[1] / 16;
    const int* src = ids;
    const int* dst = ids + E;

    float* hbuf = (float*)d_ws;                         // N*64
    float* agg  = hbuf + (size_t)N * HID;               // N*64
    float* pool = agg  + (size_t)N * HID;               // 256*64

    const int egrid   = 1536;
    const int ngrid   = (N + 31) / 32;

    // ---- layer 0 ----
    hipMemsetAsync(agg, 0, (size_t)N * HID * sizeof(float), stream);
    edge_msg<32, 16><<<egrid, 256, 0, stream>>>(H, Xe, src, dst, Mw0, Mb0, agg, E);
    node_update<32><<<ngrid, 256, 0, stream>>>(H, agg, Uw0, Ub0, hbuf, N);

    // ---- hidden layers ----
    for (int l = 0; l < 3; l++) {
        hipMemsetAsync(agg, 0, (size_t)N * HID * sizeof(float), stream);
        edge_msg<64, 16><<<egrid, 256, 0, stream>>>(hbuf, Xe, src, dst,
                                                    MwH + (size_t)l * 80 * HID,
                                                    MbH + (size_t)l * HID, agg, E);
        node_update<64><<<ngrid, 256, 0, stream>>>(hbuf, agg,
                                                   UwH + (size_t)l * 128 * HID,
                                                   UbH + (size_t)l * HID, hbuf, N);
    }

    // ---- pooling + head ----
    hipMemsetAsync(pool, 0, 256 * HID * sizeof(float), stream);
    pool_kernel<<<(N * 16 + 255) / 256, 256, 0, stream>>>(hbuf, bidx, pool, N);
    head_kernel<<<64, 256, 0, stream>>>(pool, Ww, Wb, out);
}

// Round 2
// 1691.915 us; speedup vs baseline: 2.8378x; 2.8378x over previous
//
#include <hip/hip_runtime.h>

#define HID 64

// ===========================================================================
// CSR build: histogram + scan + stable-ish permutation (order within a dst
// run is atomic-nondeterministic; sums are order-insensitive within fp32 tol)
// ===========================================================================
__global__ __launch_bounds__(256) void deg_count(const int* __restrict__ dst,
                                                 int* __restrict__ deg, int E) {
    int e = blockIdx.x * 256 + threadIdx.x;
    if (e < E) atomicAdd(&deg[dst[e]], 1);
}

// per-block exclusive scan over 2048 elements, emit block sums
__global__ __launch_bounds__(256) void scan1(const int* __restrict__ deg,
                                             int* __restrict__ rowptr,
                                             int* __restrict__ bsums, int N) {
    __shared__ int s[256];
    const int t = threadIdx.x;
    const int base = blockIdx.x * 2048 + t * 8;
    int v[8], tot = 0;
    #pragma unroll
    for (int i = 0; i < 8; i++) {
        int x = (base + i < N) ? deg[base + i] : 0;
        v[i] = tot; tot += x;
    }
    s[t] = tot; __syncthreads();
    for (int off = 1; off < 256; off <<= 1) {
        int a = (t >= off) ? s[t - off] : 0;
        __syncthreads(); s[t] += a; __syncthreads();
    }
    const int texcl = s[t] - tot;
    #pragma unroll
    for (int i = 0; i < 8; i++)
        if (base + i < N) rowptr[base + i] = texcl + v[i];
    if (t == 255) bsums[blockIdx.x] = s[255];
}

__global__ void scan2(int* bsums, int NB) {
    if (blockIdx.x == 0 && threadIdx.x == 0) {
        int run = 0;
        for (int i = 0; i < NB; i++) { int x = bsums[i]; bsums[i] = run; run += x; }
    }
}

__global__ __launch_bounds__(256) void scan3(int* __restrict__ rowptr,
                                             const int* __restrict__ bsums,
                                             int N, int E) {
    int idx = blockIdx.x * 256 + threadIdx.x;
    if (idx < N) rowptr[idx] += bsums[idx >> 11];
    if (idx == 0) rowptr[N] = E;
}

__global__ __launch_bounds__(256) void permute_k(const int* __restrict__ src,
                                                 const int* __restrict__ dst,
                                                 const int* __restrict__ rowptr,
                                                 int* __restrict__ cursor,
                                                 int* __restrict__ srcs_s,
                                                 int* __restrict__ dst_s,
                                                 int* __restrict__ eperm, int E) {
    int e = blockIdx.x * 256 + threadIdx.x;
    if (e >= E) return;
    int d = dst[e];
    int pos = rowptr[d] + atomicAdd(&cursor[d], 1);
    srcs_s[pos] = src[e];
    dst_s[pos]  = d;
    eperm[pos]  = e;
}

// ===========================================================================
// Fused edge-message + aggregation. Block owns 32 dst nodes and their
// contiguous sorted edge span. Messages via 64-edge x 64-ch GEMM tiles;
// scatter into LDS agg (run-merged LDS atomics); exclusive global agg write.
// ===========================================================================
template<int K1>
__global__ __launch_bounds__(256) void edge_agg(
    const float* __restrict__ Hn,     // [N, K1]
    const float* __restrict__ Xe,     // [E, 16] original order
    const int*   __restrict__ srcs_s, // [E] sorted by dst
    const int*   __restrict__ eperm,  // [E] sorted->orig edge id
    const int*   __restrict__ dst_s,  // [E] sorted dst
    const int*   __restrict__ rowptr, // [N+1]
    const float* __restrict__ W,      // [K1+16, 64]
    const float* __restrict__ bias,   // [64]
    float*       __restrict__ agg,    // [N, 64] exclusive write
    int N)
{
    constexpr int K   = K1 + 16;
    constexpr int KP  = K + 4;
    constexpr int AGP = HID + 4;
    __shared__ float Ws[K * HID];
    __shared__ float Xs[64 * KP];
    __shared__ float aggs[32 * AGP];
    __shared__ int   s_src[64], s_ep[64], s_ld[64];

    const int tid = threadIdx.x;

    for (int i = tid * 4; i < K * HID; i += 256 * 4)
        *(float4*)&Ws[i] = *(const float4*)&W[i];
    for (int i = tid; i < 32 * AGP; i += 256)
        aggs[i] = 0.f;

    const int nbase = blockIdx.x * 32;
    const int nend  = (nbase + 32 < N) ? nbase + 32 : N;
    const int estart = rowptr[nbase];
    const int eend   = rowptr[nend];

    const int c0  = (tid & 15) * 4;
    const int e0l = (tid >> 4) * 4;
    const float4 bvec = *(const float4*)&bias[c0];

    const int nchunks = (eend - estart + 63) / 64;
    for (int ch = 0; ch < nchunks; ch++) {
        const int p0 = estart + ch * 64;
        __syncthreads();                   // protect Xs/s_* and prior scatter
        if (tid < 64) {
            const int p = p0 + tid;
            const bool valid = p < eend;
            s_src[tid] = valid ? srcs_s[p] : 0;
            s_ep[tid]  = valid ? eperm[p]  : 0;
            s_ld[tid]  = valid ? (dst_s[p] - nbase) : -1;
        }
        __syncthreads();
        // ---- stage X tile: 4 threads per edge ----
        {
            const int el  = tid >> 2;
            const int prt = tid & 3;
            const float* hrow = Hn + (size_t)s_src[el] * K1;
            const float* xrow = Xe + (size_t)s_ep[el] * 16;
            #pragma unroll
            for (int i = prt; i < K / 4; i += 4) {
                const int k = i * 4;
                float4 v = (k < K1) ? *(const float4*)&hrow[k]
                                    : *(const float4*)&xrow[k - K1];
                *(float4*)&Xs[el * KP + k] = v;
            }
        }
        __syncthreads();

        float acc[4][4];
        #pragma unroll
        for (int i = 0; i < 4; i++)
            #pragma unroll
            for (int j = 0; j < 4; j++) acc[i][j] = 0.f;

        #pragma unroll 4
        for (int k = 0; k < K; k += 4) {
            const float4 w0 = *(const float4*)&Ws[(k + 0) * HID + c0];
            const float4 w1 = *(const float4*)&Ws[(k + 1) * HID + c0];
            const float4 w2 = *(const float4*)&Ws[(k + 2) * HID + c0];
            const float4 w3 = *(const float4*)&Ws[(k + 3) * HID + c0];
            #pragma unroll
            for (int ei = 0; ei < 4; ei++) {
                const float4 xv = *(const float4*)&Xs[(e0l + ei) * KP + k];
                acc[ei][0] += xv.x * w0.x + xv.y * w1.x + xv.z * w2.x + xv.w * w3.x;
                acc[ei][1] += xv.x * w0.y + xv.y * w1.y + xv.z * w2.y + xv.w * w3.y;
                acc[ei][2] += xv.x * w0.z + xv.y * w1.z + xv.z * w2.z + xv.w * w3.z;
                acc[ei][3] += xv.x * w0.w + xv.y * w1.w + xv.z * w2.w + xv.w * w3.w;
            }
        }

        // ---- bias + relu + run-merged LDS scatter ----
        int ld_prev = -1;
        float4 r = make_float4(0.f, 0.f, 0.f, 0.f);
        #pragma unroll
        for (int ei = 0; ei < 4; ei++) {
            const int ld = s_ld[e0l + ei];
            float4 v;
            v.x = fmaxf(acc[ei][0] + bvec.x, 0.f);
            v.y = fmaxf(acc[ei][1] + bvec.y, 0.f);
            v.z = fmaxf(acc[ei][2] + bvec.z, 0.f);
            v.w = fmaxf(acc[ei][3] + bvec.w, 0.f);
            if (ld == ld_prev) {
                r.x += v.x; r.y += v.y; r.z += v.z; r.w += v.w;
            } else {
                if (ld_prev >= 0) {
                    float* a = &aggs[ld_prev * AGP + c0];
                    atomicAdd(a + 0, r.x); atomicAdd(a + 1, r.y);
                    atomicAdd(a + 2, r.z); atomicAdd(a + 3, r.w);
                }
                r = v; ld_prev = ld;
            }
        }
        if (ld_prev >= 0) {
            float* a = &aggs[ld_prev * AGP + c0];
            atomicAdd(a + 0, r.x); atomicAdd(a + 1, r.y);
            atomicAdd(a + 2, r.z); atomicAdd(a + 3, r.w);
        }
    }

    __syncthreads();
    // ---- exclusive agg write-out ----
    for (int idx = tid; idx < 32 * 16; idx += 256) {
        const int row = idx >> 4, c4 = idx & 15;
        if (nbase + row < N)
            *(float4*)&agg[(size_t)(nbase + row) * HID + c4 * 4] =
                *(float4*)&aggs[row * AGP + c4 * 4];
    }
}

// ===========================================================================
// Node update: y = relu([Hn, Agg] @ W + b) — unchanged from R1
// ===========================================================================
template<int K1>
__global__ __launch_bounds__(256) void node_update(
    const float* __restrict__ Hn, const float* __restrict__ Agg,
    const float* __restrict__ W, const float* __restrict__ bias,
    float* __restrict__ Yout, int N)
{
    constexpr int K  = K1 + HID;
    constexpr int KP = K + 4;
    __shared__ float Ws[K * HID];
    __shared__ float Xs[32 * KP];

    const int tid = threadIdx.x;
    for (int i = tid * 4; i < K * HID; i += 256 * 4)
        *(float4*)&Ws[i] = *(const float4*)&W[i];

    const int c0  = (tid & 15) * 4;
    const int n0l = (tid >> 4) * 2;
    const float4 bvec = *(const float4*)&bias[c0];

    const int ntiles = (N + 31) / 32;
    for (int tile = blockIdx.x; tile < ntiles; tile += gridDim.x) {
        const int nbase = tile * 32;
        __syncthreads();
        {
            const int nl = tid >> 3;
            const int p  = tid & 7;
            const int n  = nbase + nl;
            if (n < N) {
                const float* hrow = Hn  + (size_t)n * K1;
                const float* arow = Agg + (size_t)n * HID;
                #pragma unroll
                for (int i = p; i < K / 4; i += 8) {
                    const int k = i * 4;
                    float4 v = (k < K1) ? *(const float4*)&hrow[k]
                                        : *(const float4*)&arow[k - K1];
                    *(float4*)&Xs[nl * KP + k] = v;
                }
            }
        }
        __syncthreads();

        float acc[2][4];
        #pragma unroll
        for (int i = 0; i < 2; i++)
            #pragma unroll
            for (int j = 0; j < 4; j++) acc[i][j] = 0.f;

        #pragma unroll 4
        for (int k = 0; k < K; k += 4) {
            const float4 w0 = *(const float4*)&Ws[(k + 0) * HID + c0];
            const float4 w1 = *(const float4*)&Ws[(k + 1) * HID + c0];
            const float4 w2 = *(const float4*)&Ws[(k + 2) * HID + c0];
            const float4 w3 = *(const float4*)&Ws[(k + 3) * HID + c0];
            #pragma unroll
            for (int ni = 0; ni < 2; ni++) {
                const float4 xv = *(const float4*)&Xs[(n0l + ni) * KP + k];
                acc[ni][0] += xv.x * w0.x + xv.y * w1.x + xv.z * w2.x + xv.w * w3.x;
                acc[ni][1] += xv.x * w0.y + xv.y * w1.y + xv.z * w2.y + xv.w * w3.y;
                acc[ni][2] += xv.x * w0.z + xv.y * w1.z + xv.z * w2.z + xv.w * w3.z;
                acc[ni][3] += xv.x * w0.w + xv.y * w1.w + xv.z * w2.w + xv.w * w3.w;
            }
        }

        #pragma unroll
        for (int ni = 0; ni < 2; ni++) {
            const int n = nbase + n0l + ni;
            if (n < N) {
                float4 o;
                o.x = fmaxf(acc[ni][0] + bvec.x, 0.f);
                o.y = fmaxf(acc[ni][1] + bvec.y, 0.f);
                o.z = fmaxf(acc[ni][2] + bvec.z, 0.f);
                o.w = fmaxf(acc[ni][3] + bvec.w, 0.f);
                *(float4*)&Yout[(size_t)n * HID + c0] = o;
            }
        }
    }
}

// ===========================================================================
// Pooling + head — unchanged
// ===========================================================================
__global__ __launch_bounds__(256) void pool_kernel(
    const float* __restrict__ Y, const int* __restrict__ bidx,
    float* __restrict__ pool, int N)
{
    const int idx = blockIdx.x * blockDim.x + threadIdx.x;
    if (idx >= N * 16) return;
    const int n = idx >> 4, c4 = idx & 15;
    const float4 v = *(const float4*)&Y[(size_t)n * HID + c4 * 4];
    float* p = pool + (size_t)bidx[n] * HID + c4 * 4;
    atomicAdd(p + 0, v.x); atomicAdd(p + 1, v.y);
    atomicAdd(p + 2, v.z); atomicAdd(p + 3, v.w);
}

__global__ __launch_bounds__(256) void head_kernel(
    const float* __restrict__ pool, const float* __restrict__ Ww,
    const float* __restrict__ Wb, float* __restrict__ out)
{
    const int g    = blockIdx.x * 4 + (threadIdx.x >> 6);
    const int lane = threadIdx.x & 63;
    float v = pool[g * HID + lane] * Ww[lane];
    #pragma unroll
    for (int off = 32; off; off >>= 1) v += __shfl_down(v, off);
    if (lane == 0) out[g] = v + Wb[0];
}

extern "C" void kernel_launch(void* const* d_in, const int* in_sizes, int n_in,
                              void* d_out, int out_size, void* d_ws, size_t ws_size,
                              hipStream_t stream) {
    const float* H    = (const float*)d_in[0];
    const float* Xe   = (const float*)d_in[1];
    const int*   ids  = (const int*)d_in[2];
    const int*   bidx = (const int*)d_in[3];
    const float* Mw0  = (const float*)d_in[4];
    const float* Mb0  = (const float*)d_in[5];
    const float* Uw0  = (const float*)d_in[6];
    const float* Ub0  = (const float*)d_in[7];
    const float* MwH  = (const float*)d_in[8];
    const float* MbH  = (const float*)d_in[9];
    const float* UwH  = (const float*)d_in[10];
    const float* UbH  = (const float*)d_in[11];
    const float* Ww   = (const float*)d_in[12];
    const float* Wb   = (const float*)d_in[13];
    float* out = (float*)d_out;

    const int N = in_sizes[0] / 32;
    const int E = in_sizes[1] / 16;
    const int* src = ids;
    const int* dst = ids + E;

    // ---- workspace layout ----
    float* hbuf = (float*)d_ws;                          // N*64
    float* agg  = hbuf + (size_t)N * HID;                // N*64
    float* pool = agg  + (size_t)N * HID;                // 256*64
    int* rowptr = (int*)(pool + 256 * HID);              // N+1
    int* deg    = rowptr + (N + 1);                      // N (also cursor)
    int* bsums  = deg + N;                               // <=4096
    int* srcs_s = bsums + 4096;                          // E
    int* dst_s  = srcs_s + E;                            // E
    int* eperm  = dst_s + E;                             // E

    const int NB = (N + 2047) / 2048;
    const int eblocks = (E + 255) / 256;
    const int ntile   = (N + 31) / 32;

    // ---- CSR build ----
    hipMemsetAsync(deg, 0, (size_t)N * sizeof(int), stream);
    deg_count<<<eblocks, 256, 0, stream>>>(dst, deg, E);
    scan1<<<NB, 256, 0, stream>>>(deg, rowptr, bsums, N);
    scan2<<<1, 64, 0, stream>>>(bsums, NB);
    scan3<<<(N + 255) / 256, 256, 0, stream>>>(rowptr, bsums, N, E);
    hipMemsetAsync(deg, 0, (size_t)N * sizeof(int), stream);
    permute_k<<<eblocks, 256, 0, stream>>>(src, dst, rowptr, deg,
                                           srcs_s, dst_s, eperm, E);

    // ---- layer 0 ----
    edge_agg<32><<<ntile, 256, 0, stream>>>(H, Xe, srcs_s, eperm, dst_s, rowptr,
                                            Mw0, Mb0, agg, N);
    node_update<32><<<ntile, 256, 0, stream>>>(H, agg, Uw0, Ub0, hbuf, N);

    // ---- hidden layers ----
    for (int l = 0; l < 3; l++) {
        edge_agg<64><<<ntile, 256, 0, stream>>>(hbuf, Xe, srcs_s, eperm, dst_s, rowptr,
                                                MwH + (size_t)l * 80 * HID,
                                                MbH + (size_t)l * HID, agg, N);
        node_update<64><<<ntile, 256, 0, stream>>>(hbuf, agg,
                                                   UwH + (size_t)l * 128 * HID,
                                                   UbH + (size_t)l * HID, hbuf, N);
    }

    // ---- pooling + head ----
    hipMemsetAsync(pool, 0, 256 * HID * sizeof(float), stream);
    pool_kernel<<<(N * 16 + 255) / 256, 256, 0, stream>>>(hbuf, bidx, pool, N);
    head_kernel<<<64, 256, 0, stream>>>(pool, Ww, Wb, out);
}

// Round 3
// 1459.062 us; speedup vs baseline: 3.2907x; 1.1596x over previous
//
#include <hip/hip_runtime.h>

#define HID 64

// ===========================================================================
// CSR build: histogram + scan + permutation (order within a dst run is
// atomic-nondeterministic; fp32 sums differ only within tolerance)
// ===========================================================================
__global__ __launch_bounds__(256) void deg_count(const int* __restrict__ dst,
                                                 int* __restrict__ deg, int E) {
    int e = blockIdx.x * 256 + threadIdx.x;
    if (e < E) atomicAdd(&deg[dst[e]], 1);
}

__global__ __launch_bounds__(256) void scan1(const int* __restrict__ deg,
                                             int* __restrict__ rowptr,
                                             int* __restrict__ bsums, int N) {
    __shared__ int s[256];
    const int t = threadIdx.x;
    const int base = blockIdx.x * 2048 + t * 8;
    int v[8], tot = 0;
    #pragma unroll
    for (int i = 0; i < 8; i++) {
        int x = (base + i < N) ? deg[base + i] : 0;
        v[i] = tot; tot += x;
    }
    s[t] = tot; __syncthreads();
    for (int off = 1; off < 256; off <<= 1) {
        int a = (t >= off) ? s[t - off] : 0;
        __syncthreads(); s[t] += a; __syncthreads();
    }
    const int texcl = s[t] - tot;
    #pragma unroll
    for (int i = 0; i < 8; i++)
        if (base + i < N) rowptr[base + i] = texcl + v[i];
    if (t == 255) bsums[blockIdx.x] = s[255];
}

__global__ void scan2(int* bsums, int NB) {
    if (blockIdx.x == 0 && threadIdx.x == 0) {
        int run = 0;
        for (int i = 0; i < NB; i++) { int x = bsums[i]; bsums[i] = run; run += x; }
    }
}

__global__ __launch_bounds__(256) void scan3(int* __restrict__ rowptr,
                                             const int* __restrict__ bsums,
                                             int N, int E) {
    int idx = blockIdx.x * 256 + threadIdx.x;
    if (idx < N) rowptr[idx] += bsums[idx >> 11];
    if (idx == 0) rowptr[N] = E;
}

__global__ __launch_bounds__(256) void permute_k(const int* __restrict__ src,
                                                 const int* __restrict__ dst,
                                                 const int* __restrict__ rowptr,
                                                 int* __restrict__ cursor,
                                                 int* __restrict__ srcs_s,
                                                 int* __restrict__ dst_s,
                                                 int* __restrict__ eperm, int E) {
    int e = blockIdx.x * 256 + threadIdx.x;
    if (e >= E) return;
    int d = dst[e];
    int pos = rowptr[d] + atomicAdd(&cursor[d], 1);
    srcs_s[pos] = src[e];
    dst_s[pos]  = d;
    eperm[pos]  = e;
}

// ===========================================================================
// pm_gemm: PM = Hn @ W_top + bias   (tiny GEMM, K1 = 32 or 64)
// ===========================================================================
template<int K1>
__global__ __launch_bounds__(256) void pm_gemm(
    const float* __restrict__ Hn,    // [N, K1]
    const float* __restrict__ W,     // [K1, 64] (top rows of Mw)
    const float* __restrict__ bias,  // [64]
    float*       __restrict__ PM,    // [N, 64]
    int N)
{
    constexpr int KP = K1 + 4;
    __shared__ float Ws[K1 * HID];
    __shared__ float Xs[32 * KP];

    const int tid = threadIdx.x;
    for (int i = tid * 4; i < K1 * HID; i += 256 * 4)
        *(float4*)&Ws[i] = *(const float4*)&W[i];

    const int c0  = (tid & 15) * 4;
    const int n0l = (tid >> 4) * 2;
    const float4 bvec = *(const float4*)&bias[c0];

    const int ntiles = (N + 31) / 32;
    for (int tile = blockIdx.x; tile < ntiles; tile += gridDim.x) {
        const int nbase = tile * 32;
        __syncthreads();
        {
            const int nl = tid >> 3;
            const int p  = tid & 7;
            const int n  = nbase + nl;
            if (n < N) {
                const float* hrow = Hn + (size_t)n * K1;
                #pragma unroll
                for (int i = p; i < K1 / 4; i += 8)
                    *(float4*)&Xs[nl * KP + i * 4] = *(const float4*)&hrow[i * 4];
            }
        }
        __syncthreads();

        float acc[2][4];
        #pragma unroll
        for (int ni = 0; ni < 2; ni++) {
            acc[ni][0] = bvec.x; acc[ni][1] = bvec.y;
            acc[ni][2] = bvec.z; acc[ni][3] = bvec.w;
        }

        #pragma unroll 4
        for (int k = 0; k < K1; k += 4) {
            const float4 w0 = *(const float4*)&Ws[(k + 0) * HID + c0];
            const float4 w1 = *(const float4*)&Ws[(k + 1) * HID + c0];
            const float4 w2 = *(const float4*)&Ws[(k + 2) * HID + c0];
            const float4 w3 = *(const float4*)&Ws[(k + 3) * HID + c0];
            #pragma unroll
            for (int ni = 0; ni < 2; ni++) {
                const float4 xv = *(const float4*)&Xs[(n0l + ni) * KP + k];
                acc[ni][0] += xv.x * w0.x + xv.y * w1.x + xv.z * w2.x + xv.w * w3.x;
                acc[ni][1] += xv.x * w0.y + xv.y * w1.y + xv.z * w2.y + xv.w * w3.y;
                acc[ni][2] += xv.x * w0.z + xv.y * w1.z + xv.z * w2.z + xv.w * w3.z;
                acc[ni][3] += xv.x * w0.w + xv.y * w1.w + xv.z * w2.w + xv.w * w3.w;
            }
        }

        #pragma unroll
        for (int ni = 0; ni < 2; ni++) {
            const int n = nbase + n0l + ni;
            if (n < N) {
                float4 o = make_float4(acc[ni][0], acc[ni][1], acc[ni][2], acc[ni][3]);
                *(float4*)&PM[(size_t)n * HID + c0] = o;
            }
        }
    }
}

// ===========================================================================
// Fused edge kernel: m = relu(PM[src] + Xe[e] @ Wb); agg[dst] += m
// Block owns 32 dst nodes + their sorted edge span. Wb in registers.
// ===========================================================================
__global__ __launch_bounds__(256) void edge_agg2(
    const float* __restrict__ PM,     // [N, 64] = Hn @ W_top + bias
    const float* __restrict__ Xe,     // [E, 16] original order
    const int*   __restrict__ srcs_s, // [E] sorted by dst
    const int*   __restrict__ eperm,  // [E] sorted->orig edge id
    const int*   __restrict__ dst_s,  // [E] sorted dst
    const int*   __restrict__ rowptr, // [N+1]
    const float* __restrict__ Wb,     // [16, 64] bottom rows of Mw
    float*       __restrict__ agg,    // [N, 64] exclusive write
    int N)
{
    constexpr int XP  = 20;           // padded Xe row stride (2-way conflicts = free)
    constexpr int AGP = HID + 4;
    __shared__ float Xs[64 * XP];     // 5.1 KB
    __shared__ float aggs[32 * AGP];  // 8.7 KB

    const int tid = threadIdx.x;
    const int c0  = (tid & 15) * 4;
    const int e0l = (tid >> 4) * 4;

    // Wb fragment in registers: 16 float4 per thread
    float4 wreg[16];
    #pragma unroll
    for (int k = 0; k < 16; k++)
        wreg[k] = *(const float4*)&Wb[k * HID + c0];

    for (int i = tid; i < 32 * AGP; i += 256) aggs[i] = 0.f;

    const int nbase  = blockIdx.x * 32;
    const int nend   = (nbase + 32 < N) ? nbase + 32 : N;
    const int estart = rowptr[nbase];
    const int eend   = rowptr[nend];

    const int nchunks = (eend - estart + 63) / 64;
    for (int ch = 0; ch < nchunks; ch++) {
        const int p0 = estart + ch * 64;
        __syncthreads();                       // protect Xs from previous compute
        // ---- stage Xe tile (4 threads per edge, direct eperm read) ----
        {
            const int el = tid >> 2;
            const int p  = tid & 3;
            const int pe = p0 + el;
            if (pe < eend) {
                const int ep = eperm[pe];      // 4-lane broadcast, L1 hit
                *(float4*)&Xs[el * XP + p * 4] =
                    *(const float4*)&Xe[(size_t)ep * 16 + p * 4];
            }
        }
        __syncthreads();

        // ---- gather PM rows + edge metadata (16-lane broadcast reads) ----
        float4 acc[4];
        int ld[4];
        #pragma unroll
        for (int ei = 0; ei < 4; ei++) {
            const int pe = p0 + e0l + ei;
            if (pe < eend) {
                const int s = srcs_s[pe];
                acc[ei] = *(const float4*)&PM[(size_t)s * HID + c0];
                ld[ei]  = dst_s[pe] - nbase;
            } else {
                acc[ei] = make_float4(0.f, 0.f, 0.f, 0.f);
                ld[ei]  = -1;
            }
        }

        // ---- K=16 FMA: acc += Xe_row @ Wb ----
        #pragma unroll
        for (int ei = 0; ei < 4; ei++) {
            const float* xr = &Xs[(e0l + ei) * XP];
            #pragma unroll
            for (int k4 = 0; k4 < 4; k4++) {
                const float4 xv = *(const float4*)&xr[k4 * 4];
                const float4 w0 = wreg[k4 * 4 + 0];
                const float4 w1 = wreg[k4 * 4 + 1];
                const float4 w2 = wreg[k4 * 4 + 2];
                const float4 w3 = wreg[k4 * 4 + 3];
                acc[ei].x += xv.x * w0.x + xv.y * w1.x + xv.z * w2.x + xv.w * w3.x;
                acc[ei].y += xv.x * w0.y + xv.y * w1.y + xv.z * w2.y + xv.w * w3.y;
                acc[ei].z += xv.x * w0.z + xv.y * w1.z + xv.z * w2.z + xv.w * w3.z;
                acc[ei].w += xv.x * w0.w + xv.y * w1.w + xv.z * w2.w + xv.w * w3.w;
            }
        }

        // ---- relu + run-merged LDS scatter ----
        int ld_prev = -1;
        float4 r = make_float4(0.f, 0.f, 0.f, 0.f);
        #pragma unroll
        for (int ei = 0; ei < 4; ei++) {
            float4 v;
            v.x = fmaxf(acc[ei].x, 0.f);
            v.y = fmaxf(acc[ei].y, 0.f);
            v.z = fmaxf(acc[ei].z, 0.f);
            v.w = fmaxf(acc[ei].w, 0.f);
            if (ld[ei] == ld_prev) {
                r.x += v.x; r.y += v.y; r.z += v.z; r.w += v.w;
            } else {
                if (ld_prev >= 0) {
                    float* a = &aggs[ld_prev * AGP + c0];
                    atomicAdd(a + 0, r.x); atomicAdd(a + 1, r.y);
                    atomicAdd(a + 2, r.z); atomicAdd(a + 3, r.w);
                }
                r = v; ld_prev = ld[ei];
            }
        }
        if (ld_prev >= 0) {
            float* a = &aggs[ld_prev * AGP + c0];
            atomicAdd(a + 0, r.x); atomicAdd(a + 1, r.y);
            atomicAdd(a + 2, r.z); atomicAdd(a + 3, r.w);
        }
    }

    __syncthreads();
    for (int idx = tid; idx < 32 * 16; idx += 256) {
        const int row = idx >> 4, c4 = idx & 15;
        if (nbase + row < N)
            *(float4*)&agg[(size_t)(nbase + row) * HID + c4 * 4] =
                *(float4*)&aggs[row * AGP + c4 * 4];
    }
}

// ===========================================================================
// Node update: y = relu([Hn, Agg] @ W + b)
// ===========================================================================
template<int K1>
__global__ __launch_bounds__(256) void node_update(
    const float* __restrict__ Hn, const float* __restrict__ Agg,
    const float* __restrict__ W, const float* __restrict__ bias,
    float* __restrict__ Yout, int N)
{
    constexpr int K  = K1 + HID;
    constexpr int KP = K + 4;
    __shared__ float Ws[K * HID];
    __shared__ float Xs[32 * KP];

    const int tid = threadIdx.x;
    for (int i = tid * 4; i < K * HID; i += 256 * 4)
        *(float4*)&Ws[i] = *(const float4*)&W[i];

    const int c0  = (tid & 15) * 4;
    const int n0l = (tid >> 4) * 2;
    const float4 bvec = *(const float4*)&bias[c0];

    const int ntiles = (N + 31) / 32;
    for (int tile = blockIdx.x; tile < ntiles; tile += gridDim.x) {
        const int nbase = tile * 32;
        __syncthreads();
        {
            const int nl = tid >> 3;
            const int p  = tid & 7;
            const int n  = nbase + nl;
            if (n < N) {
                const float* hrow = Hn  + (size_t)n * K1;
                const float* arow = Agg + (size_t)n * HID;
                #pragma unroll
                for (int i = p; i < K / 4; i += 8) {
                    const int k = i * 4;
                    float4 v = (k < K1) ? *(const float4*)&hrow[k]
                                        : *(const float4*)&arow[k - K1];
                    *(float4*)&Xs[nl * KP + k] = v;
                }
            }
        }
        __syncthreads();

        float acc[2][4];
        #pragma unroll
        for (int i = 0; i < 2; i++)
            #pragma unroll
            for (int j = 0; j < 4; j++) acc[i][j] = 0.f;

        #pragma unroll 4
        for (int k = 0; k < K; k += 4) {
            const float4 w0 = *(const float4*)&Ws[(k + 0) * HID + c0];
            const float4 w1 = *(const float4*)&Ws[(k + 1) * HID + c0];
            const float4 w2 = *(const float4*)&Ws[(k + 2) * HID + c0];
            const float4 w3 = *(const float4*)&Ws[(k + 3) * HID + c0];
            #pragma unroll
            for (int ni = 0; ni < 2; ni++) {
                const float4 xv = *(const float4*)&Xs[(n0l + ni) * KP + k];
                acc[ni][0] += xv.x * w0.x + xv.y * w1.x + xv.z * w2.x + xv.w * w3.x;
                acc[ni][1] += xv.x * w0.y + xv.y * w1.y + xv.z * w2.y + xv.w * w3.y;
                acc[ni][2] += xv.x * w0.z + xv.y * w1.z + xv.z * w2.z + xv.w * w3.z;
                acc[ni][3] += xv.x * w0.w + xv.y * w1.w + xv.z * w2.w + xv.w * w3.w;
            }
        }

        #pragma unroll
        for (int ni = 0; ni < 2; ni++) {
            const int n = nbase + n0l + ni;
            if (n < N) {
                float4 o;
                o.x = fmaxf(acc[ni][0] + bvec.x, 0.f);
                o.y = fmaxf(acc[ni][1] + bvec.y, 0.f);
                o.z = fmaxf(acc[ni][2] + bvec.z, 0.f);
                o.w = fmaxf(acc[ni][3] + bvec.w, 0.f);
                *(float4*)&Yout[(size_t)n * HID + c0] = o;
            }
        }
    }
}

// ===========================================================================
// Pooling + head
// ===========================================================================
__global__ __launch_bounds__(256) void pool_kernel(
    const float* __restrict__ Y, const int* __restrict__ bidx,
    float* __restrict__ pool, int N)
{
    const int idx = blockIdx.x * blockDim.x + threadIdx.x;
    if (idx >= N * 16) return;
    const int n = idx >> 4, c4 = idx & 15;
    const float4 v = *(const float4*)&Y[(size_t)n * HID + c4 * 4];
    float* p = pool + (size_t)bidx[n] * HID + c4 * 4;
    atomicAdd(p + 0, v.x); atomicAdd(p + 1, v.y);
    atomicAdd(p + 2, v.z); atomicAdd(p + 3, v.w);
}

__global__ __launch_bounds__(256) void head_kernel(
    const float* __restrict__ pool, const float* __restrict__ Ww,
    const float* __restrict__ Wb, float* __restrict__ out)
{
    const int g    = blockIdx.x * 4 + (threadIdx.x >> 6);
    const int lane = threadIdx.x & 63;
    float v = pool[g * HID + lane] * Ww[lane];
    #pragma unroll
    for (int off = 32; off; off >>= 1) v += __shfl_down(v, off);
    if (lane == 0) out[g] = v + Wb[0];
}

extern "C" void kernel_launch(void* const* d_in, const int* in_sizes, int n_in,
                              void* d_out, int out_size, void* d_ws, size_t ws_size,
                              hipStream_t stream) {
    const float* H    = (const float*)d_in[0];
    const float* Xe   = (const float*)d_in[1];
    const int*   ids  = (const int*)d_in[2];
    const int*   bidx = (const int*)d_in[3];
    const float* Mw0  = (const float*)d_in[4];
    const float* Mb0  = (const float*)d_in[5];
    const float* Uw0  = (const float*)d_in[6];
    const float* Ub0  = (const float*)d_in[7];
    const float* MwH  = (const float*)d_in[8];
    const float* MbH  = (const float*)d_in[9];
    const float* UwH  = (const float*)d_in[10];
    const float* UbH  = (const float*)d_in[11];
    const float* Ww   = (const float*)d_in[12];
    const float* Wb   = (const float*)d_in[13];
    float* out = (float*)d_out;

    const int N = in_sizes[0] / 32;
    const int E = in_sizes[1] / 16;
    const int* src = ids;
    const int* dst = ids + E;

    // ---- workspace layout ----
    float* hbuf = (float*)d_ws;                          // N*64
    float* agg  = hbuf + (size_t)N * HID;                // N*64
    float* PM   = agg  + (size_t)N * HID;                // N*64
    float* pool = PM   + (size_t)N * HID;                // 256*64
    int* rowptr = (int*)(pool + 256 * HID);              // N+1
    int* deg    = rowptr + (N + 1);                      // N (also cursor)
    int* bsums  = deg + N;                               // <=4096
    int* srcs_s = bsums + 4096;                          // E
    int* dst_s  = srcs_s + E;                            // E
    int* eperm  = dst_s + E;                             // E

    const int NB = (N + 2047) / 2048;
    const int eblocks = (E + 255) / 256;
    const int ntile   = (N + 31) / 32;

    // ---- CSR build ----
    hipMemsetAsync(deg, 0, (size_t)N * sizeof(int), stream);
    deg_count<<<eblocks, 256, 0, stream>>>(dst, deg, E);
    scan1<<<NB, 256, 0, stream>>>(deg, rowptr, bsums, N);
    scan2<<<1, 64, 0, stream>>>(bsums, NB);
    scan3<<<(N + 255) / 256, 256, 0, stream>>>(rowptr, bsums, N, E);
    hipMemsetAsync(deg, 0, (size_t)N * sizeof(int), stream);
    permute_k<<<eblocks, 256, 0, stream>>>(src, dst, rowptr, deg,
                                           srcs_s, dst_s, eperm, E);

    // ---- layer 0 (K1 = 32) ----
    pm_gemm<32><<<ntile, 256, 0, stream>>>(H, Mw0, Mb0, PM, N);
    edge_agg2<<<ntile, 256, 0, stream>>>(PM, Xe, srcs_s, eperm, dst_s, rowptr,
                                         Mw0 + 32 * HID, agg, N);
    node_update<32><<<ntile, 256, 0, stream>>>(H, agg, Uw0, Ub0, hbuf, N);

    // ---- hidden layers (K1 = 64) ----
    for (int l = 0; l < 3; l++) {
        const float* Mw = MwH + (size_t)l * 80 * HID;
        pm_gemm<64><<<ntile, 256, 0, stream>>>(hbuf, Mw, MbH + (size_t)l * HID, PM, N);
        edge_agg2<<<ntile, 256, 0, stream>>>(PM, Xe, srcs_s, eperm, dst_s, rowptr,
                                             Mw + 64 * HID, agg, N);
        node_update<64><<<ntile, 256, 0, stream>>>(hbuf, agg,
                                                   UwH + (size_t)l * 128 * HID,
                                                   UbH + (size_t)l * HID, hbuf, N);
    }

    // ---- pooling + head ----
    hipMemsetAsync(pool, 0, 256 * HID * sizeof(float), stream);
    pool_kernel<<<(N * 16 + 255) / 256, 256, 0, stream>>>(hbuf, bidx, pool, N);
    head_kernel<<<64, 256, 0, stream>>>(pool, Ww, Wb, out);
}

// Round 4
// 1290.502 us; speedup vs baseline: 3.7205x; 1.1306x over previous
//
#include <hip/hip_runtime.h>

#define HID 64

// ===========================================================================
// CSR build: histogram + scan + permutation
// ===========================================================================
__global__ __launch_bounds__(256) void deg_count(const int* __restrict__ dst,
                                                 int* __restrict__ deg, int E) {
    int e = blockIdx.x * 256 + threadIdx.x;
    if (e < E) atomicAdd(&deg[dst[e]], 1);
}

__global__ __launch_bounds__(256) void scan1(const int* __restrict__ deg,
                                             int* __restrict__ rowptr,
                                             int* __restrict__ bsums, int N) {
    __shared__ int s[256];
    const int t = threadIdx.x;
    const int base = blockIdx.x * 2048 + t * 8;
    int v[8], tot = 0;
    #pragma unroll
    for (int i = 0; i < 8; i++) {
        int x = (base + i < N) ? deg[base + i] : 0;
        v[i] = tot; tot += x;
    }
    s[t] = tot; __syncthreads();
    for (int off = 1; off < 256; off <<= 1) {
        int a = (t >= off) ? s[t - off] : 0;
        __syncthreads(); s[t] += a; __syncthreads();
    }
    const int texcl = s[t] - tot;
    #pragma unroll
    for (int i = 0; i < 8; i++)
        if (base + i < N) rowptr[base + i] = texcl + v[i];
    if (t == 255) bsums[blockIdx.x] = s[255];
}

__global__ void scan2(int* bsums, int NB) {
    if (blockIdx.x == 0 && threadIdx.x == 0) {
        int run = 0;
        for (int i = 0; i < NB; i++) { int x = bsums[i]; bsums[i] = run; run += x; }
    }
}

__global__ __launch_bounds__(256) void scan3(int* __restrict__ rowptr,
                                             const int* __restrict__ bsums,
                                             int N, int E) {
    int idx = blockIdx.x * 256 + threadIdx.x;
    if (idx < N) rowptr[idx] += bsums[idx >> 11];
    if (idx == 0) rowptr[N] = E;
}

__global__ __launch_bounds__(256) void permute_k(const int* __restrict__ src,
                                                 const int* __restrict__ dst,
                                                 const int* __restrict__ rowptr,
                                                 int* __restrict__ cursor,
                                                 int2* __restrict__ pair_s,
                                                 int* __restrict__ eperm, int E) {
    int e = blockIdx.x * 256 + threadIdx.x;
    if (e >= E) return;
    int d = dst[e];
    int pos = rowptr[d] + atomicAdd(&cursor[d], 1);
    pair_s[pos] = make_int2(src[e], d);
    eperm[pos]  = e;
}

// ===========================================================================
// pm_dual: PMT[n] = [ h@Wm_top + bm  |  h@Wu_top + bu ]   (N x 128)
// One 32-node tile per block; 4 nodes x 4 ch per thread.
// ===========================================================================
template<int K1>
__global__ __launch_bounds__(256) void pm_dual(
    const float* __restrict__ Hn,   // [N, K1]
    const float* __restrict__ Wm,   // [K1, 64] (top of Mw)
    const float* __restrict__ bm,   // [64]
    const float* __restrict__ Wu,   // [K1, 64] (top of Uw)
    const float* __restrict__ bu,   // [64]
    float*       __restrict__ PMT,  // [N, 128]
    int N)
{
    constexpr int KP = K1 + 4;
    constexpr int P4 = K1 / 4;
    __shared__ float Ws[K1 * 128];
    __shared__ float Xs[32 * KP];

    const int tid = threadIdx.x;
    // stage cat weights: row k = [Wm[k,:] | Wu[k,:]]
    for (int i = tid; i < K1 * 32; i += 256) {
        const int row = i >> 5, c4 = i & 31;
        float4 v = (c4 < 16) ? *(const float4*)&Wm[row * 64 + c4 * 4]
                             : *(const float4*)&Wu[row * 64 + (c4 - 16) * 4];
        *(float4*)&Ws[row * 128 + c4 * 4] = v;
    }
    // stage 32 node rows
    const int nbase = blockIdx.x * 32;
    for (int i = tid; i < 32 * P4; i += 256) {
        const int nl = i / P4, part = i % P4;
        const int n = nbase + nl;
        if (n < N)
            *(float4*)&Xs[nl * KP + part * 4] =
                *(const float4*)&Hn[(size_t)n * K1 + part * 4];
    }
    __syncthreads();

    const int c0 = (tid & 31) * 4;
    const int n0 = (tid >> 5) * 4;
    const float4 bv = (c0 < 64) ? *(const float4*)&bm[c0]
                                : *(const float4*)&bu[c0 - 64];

    float4 acc[4];
    #pragma unroll
    for (int i = 0; i < 4; i++) acc[i] = bv;

    #pragma unroll 4
    for (int k = 0; k < K1; k += 4) {
        const float4 w0 = *(const float4*)&Ws[(k + 0) * 128 + c0];
        const float4 w1 = *(const float4*)&Ws[(k + 1) * 128 + c0];
        const float4 w2 = *(const float4*)&Ws[(k + 2) * 128 + c0];
        const float4 w3 = *(const float4*)&Ws[(k + 3) * 128 + c0];
        #pragma unroll
        for (int ni = 0; ni < 4; ni++) {
            const float4 xv = *(const float4*)&Xs[(n0 + ni) * KP + k];
            acc[ni].x += xv.x * w0.x + xv.y * w1.x + xv.z * w2.x + xv.w * w3.x;
            acc[ni].y += xv.x * w0.y + xv.y * w1.y + xv.z * w2.y + xv.w * w3.y;
            acc[ni].z += xv.x * w0.z + xv.y * w1.z + xv.z * w2.z + xv.w * w3.z;
            acc[ni].w += xv.x * w0.w + xv.y * w1.w + xv.z * w2.w + xv.w * w3.w;
        }
    }

    #pragma unroll
    for (int ni = 0; ni < 4; ni++) {
        const int n = nbase + n0 + ni;
        if (n < N) *(float4*)&PMT[(size_t)n * 128 + c0] = acc[ni];
    }
}

// ===========================================================================
// edge_fused: aggs = sum_e relu(PM[src] + Xe@Mw_bot)  (wave-independent loop)
//             y[n] = relu(T[n] + aggs[n] @ Uw_bot)    (fused tail GEMM)
// Block owns 32 dst nodes; PM = PMT[:,0:64], T = PMT[:,64:128].
// ===========================================================================
__global__ __launch_bounds__(256) void edge_fused(
    const float* __restrict__ PMT,    // [N, 128]
    const float* __restrict__ Xe,     // [E, 16]
    const int2*  __restrict__ pair_s, // [E] (src, dst) sorted by dst
    const int*   __restrict__ eperm,  // [E]
    const int*   __restrict__ rowptr, // [N+1]
    const float* __restrict__ Mwb,    // [16, 64] bottom of Mw
    const float* __restrict__ Uwb,    // [64, 64] bottom of Uw
    float*       __restrict__ Yout,   // [N, 64]
    int N)
{
    constexpr int AGP = HID + 4;
    constexpr int UP  = HID + 4;
    __shared__ float aggs[32 * AGP];   // 8.7 KB
    __shared__ float Ub[64 * UP];      // 17.4 KB
    __shared__ float Xs[4 * 16 * 20];  // 5.0 KB (per-wave slices)

    const int tid  = threadIdx.x;
    const int wv   = tid >> 6;
    const int lane = tid & 63;
    const int cg   = lane & 15;
    const int c0   = cg * 4;
    const int g    = lane >> 4;

    // stage Uw_bot into LDS
    for (int i = tid; i < 64 * 16; i += 256) {
        const int r = i >> 4, c4 = i & 15;
        *(float4*)&Ub[r * UP + c4 * 4] = *(const float4*)&Uwb[r * 64 + c4 * 4];
    }
    for (int i = tid; i < 32 * AGP; i += 256) aggs[i] = 0.f;

    // Mw_bot column slice in registers
    float4 wreg[16];
    #pragma unroll
    for (int k = 0; k < 16; k++)
        wreg[k] = *(const float4*)&Mwb[k * 64 + c0];

    const int nbase  = blockIdx.x * 32;
    const int nend   = (nbase + 32 < N) ? nbase + 32 : N;
    const int estart = rowptr[nbase];
    const int eend   = rowptr[nend];
    __syncthreads();

    float* Xw = &Xs[wv * 320];

    // ---- wave-independent 16-edge chunks, no block barriers ----
    for (int p0 = estart + wv * 16; p0 < eend; p0 += 64) {
        // stage 16 Xe rows (64 lanes x float4)
        {
            const int el = lane >> 2, part = lane & 3;
            const int pe = p0 + el;
            if (pe < eend) {
                const int ep = eperm[pe];
                *(float4*)&Xw[el * 20 + part * 4] =
                    *(const float4*)&Xe[(size_t)ep * 16 + part * 4];
            }
        }
        // wave-internal RAW on LDS: compiler inserts lgkmcnt waits

        int ld_prev = -1;
        float4 racc = make_float4(0.f, 0.f, 0.f, 0.f);
        #pragma unroll
        for (int s = 0; s < 4; s++) {
            const int pe = p0 + g * 4 + s;
            if (pe < eend) {
                const int2 sd = pair_s[pe];
                float4 acc = *(const float4*)&PMT[(size_t)sd.x * 128 + c0];
                const float* xr = &Xw[(g * 4 + s) * 20];
                #pragma unroll
                for (int k4 = 0; k4 < 4; k4++) {
                    const float4 xv = *(const float4*)&xr[k4 * 4];
                    const float4 w0 = wreg[k4 * 4 + 0];
                    const float4 w1 = wreg[k4 * 4 + 1];
                    const float4 w2 = wreg[k4 * 4 + 2];
                    const float4 w3 = wreg[k4 * 4 + 3];
                    acc.x += xv.x * w0.x + xv.y * w1.x + xv.z * w2.x + xv.w * w3.x;
                    acc.y += xv.x * w0.y + xv.y * w1.y + xv.z * w2.y + xv.w * w3.y;
                    acc.z += xv.x * w0.z + xv.y * w1.z + xv.z * w2.z + xv.w * w3.z;
                    acc.w += xv.x * w0.w + xv.y * w1.w + xv.z * w2.w + xv.w * w3.w;
                }
                float4 v;
                v.x = fmaxf(acc.x, 0.f); v.y = fmaxf(acc.y, 0.f);
                v.z = fmaxf(acc.z, 0.f); v.w = fmaxf(acc.w, 0.f);
                const int ld = sd.y - nbase;
                if (ld == ld_prev) {
                    racc.x += v.x; racc.y += v.y; racc.z += v.z; racc.w += v.w;
                } else {
                    if (ld_prev >= 0) {
                        float* a = &aggs[ld_prev * AGP + c0];
                        atomicAdd(a + 0, racc.x); atomicAdd(a + 1, racc.y);
                        atomicAdd(a + 2, racc.z); atomicAdd(a + 3, racc.w);
                    }
                    racc = v; ld_prev = ld;
                }
            }
        }
        if (ld_prev >= 0) {
            float* a = &aggs[ld_prev * AGP + c0];
            atomicAdd(a + 0, racc.x); atomicAdd(a + 1, racc.y);
            atomicAdd(a + 2, racc.z); atomicAdd(a + 3, racc.w);
        }
    }

    __syncthreads();

    // ---- fused node update: y = relu(T + aggs @ Uw_bot) ----
    {
        const int c0t = (tid & 15) * 4;
        const int r0  = tid >> 4;          // rows r0 and r0+16
        const int r1  = r0 + 16;
        const int n0g = nbase + r0, n1g = nbase + r1;
        float4 acc0 = (n0g < N) ? *(const float4*)&PMT[(size_t)n0g * 128 + 64 + c0t]
                                : make_float4(0.f, 0.f, 0.f, 0.f);
        float4 acc1 = (n1g < N) ? *(const float4*)&PMT[(size_t)n1g * 128 + 64 + c0t]
                                : make_float4(0.f, 0.f, 0.f, 0.f);
        #pragma unroll 4
        for (int k = 0; k < 64; k += 4) {
            const float4 w0 = *(const float4*)&Ub[(k + 0) * UP + c0t];
            const float4 w1 = *(const float4*)&Ub[(k + 1) * UP + c0t];
            const float4 w2 = *(const float4*)&Ub[(k + 2) * UP + c0t];
            const float4 w3 = *(const float4*)&Ub[(k + 3) * UP + c0t];
            const float4 x0 = *(const float4*)&aggs[r0 * AGP + k];
            const float4 x1 = *(const float4*)&aggs[r1 * AGP + k];
            acc0.x += x0.x * w0.x + x0.y * w1.x + x0.z * w2.x + x0.w * w3.x;
            acc0.y += x0.x * w0.y + x0.y * w1.y + x0.z * w2.y + x0.w * w3.y;
            acc0.z += x0.x * w0.z + x0.y * w1.z + x0.z * w2.z + x0.w * w3.z;
            acc0.w += x0.x * w0.w + x0.y * w1.w + x0.z * w2.w + x0.w * w3.w;
            acc1.x += x1.x * w0.x + x1.y * w1.x + x1.z * w2.x + x1.w * w3.x;
            acc1.y += x1.x * w0.y + x1.y * w1.y + x1.z * w2.y + x1.w * w3.y;
            acc1.z += x1.x * w0.z + x1.y * w1.z + x1.z * w2.z + x1.w * w3.z;
            acc1.w += x1.x * w0.w + x1.y * w1.w + x1.z * w2.w + x1.w * w3.w;
        }
        if (n0g < N) {
            float4 o;
            o.x = fmaxf(acc0.x, 0.f); o.y = fmaxf(acc0.y, 0.f);
            o.z = fmaxf(acc0.z, 0.f); o.w = fmaxf(acc0.w, 0.f);
            *(float4*)&Yout[(size_t)n0g * HID + c0t] = o;
        }
        if (n1g < N) {
            float4 o;
            o.x = fmaxf(acc1.x, 0.f); o.y = fmaxf(acc1.y, 0.f);
            o.z = fmaxf(acc1.z, 0.f); o.w = fmaxf(acc1.w, 0.f);
            *(float4*)&Yout[(size_t)n1g * HID + c0t] = o;
        }
    }
}

// ===========================================================================
// pool_head: out[g] = (sum_{n in graph g} y[n]) . Ww + Wb
// batch_idx is sorted -> binary search the segment, no atomics.
// ===========================================================================
__global__ __launch_bounds__(256) void pool_head(
    const float* __restrict__ Y, const int* __restrict__ bidx,
    const float* __restrict__ Ww, const float* __restrict__ Wb,
    float* __restrict__ out, int N)
{
    const int g = blockIdx.x;
    int a = 0, b = N;
    while (a < b) { int m = (a + b) >> 1; if (bidx[m] < g) a = m + 1; else b = m; }
    const int lo = a;
    b = N;
    while (a < b) { int m = (a + b) >> 1; if (bidx[m] < g + 1) a = m + 1; else b = m; }
    const int hi = a;

    const int tid = threadIdx.x;
    const int c4 = tid & 15, nl = tid >> 4;
    float4 s = make_float4(0.f, 0.f, 0.f, 0.f);
    for (int n = lo + nl; n < hi; n += 16) {
        const float4 v = *(const float4*)&Y[(size_t)n * HID + c4 * 4];
        s.x += v.x; s.y += v.y; s.z += v.z; s.w += v.w;
    }
    __shared__ float red[16 * 68];
    *(float4*)&red[nl * 68 + c4 * 4] = s;
    __syncthreads();
    if (tid < 64) {
        float t = 0.f;
        #pragma unroll
        for (int r = 0; r < 16; r++) t += red[r * 68 + tid];
        t *= Ww[tid];
        #pragma unroll
        for (int off = 32; off; off >>= 1) t += __shfl_down(t, off);
        if (tid == 0) out[g] = t + Wb[0];
    }
}

extern "C" void kernel_launch(void* const* d_in, const int* in_sizes, int n_in,
                              void* d_out, int out_size, void* d_ws, size_t ws_size,
                              hipStream_t stream) {
    const float* H    = (const float*)d_in[0];
    const float* Xe   = (const float*)d_in[1];
    const int*   ids  = (const int*)d_in[2];
    const int*   bidx = (const int*)d_in[3];
    const float* Mw0  = (const float*)d_in[4];
    const float* Mb0  = (const float*)d_in[5];
    const float* Uw0  = (const float*)d_in[6];
    const float* Ub0  = (const float*)d_in[7];
    const float* MwH  = (const float*)d_in[8];   // [3, 80, 64]
    const float* MbH  = (const float*)d_in[9];
    const float* UwH  = (const float*)d_in[10];  // [3, 128, 64]
    const float* UbH  = (const float*)d_in[11];
    const float* Ww   = (const float*)d_in[12];
    const float* Wb   = (const float*)d_in[13];
    float* out = (float*)d_out;

    const int N = in_sizes[0] / 32;
    const int E = in_sizes[1] / 16;
    const int* src = ids;
    const int* dst = ids + E;

    // ---- workspace ----
    float* hbuf = (float*)d_ws;                    // N*64
    float* PMT  = hbuf + (size_t)N * HID;          // N*128
    int* rowptr = (int*)(PMT + (size_t)N * 128);   // N+1
    int* deg    = rowptr + (N + 1);                // N
    int* bsums  = deg + N;                         // <=4096
    int* eperm  = bsums + 4096;                    // E
    int2* pair_s = (int2*)(eperm + E);             // E int2 (8B aligned: offset even)

    const int NB = (N + 2047) / 2048;
    const int eblocks = (E + 255) / 256;
    const int ntile   = (N + 31) / 32;

    // ---- CSR build ----
    hipMemsetAsync(deg, 0, (size_t)N * sizeof(int), stream);
    deg_count<<<eblocks, 256, 0, stream>>>(dst, deg, E);
    scan1<<<NB, 256, 0, stream>>>(deg, rowptr, bsums, N);
    scan2<<<1, 64, 0, stream>>>(bsums, NB);
    scan3<<<(N + 255) / 256, 256, 0, stream>>>(rowptr, bsums, N, E);
    hipMemsetAsync(deg, 0, (size_t)N * sizeof(int), stream);
    permute_k<<<eblocks, 256, 0, stream>>>(src, dst, rowptr, deg,
                                           pair_s, eperm, E);

    // ---- layer 0 (K1=32) ----
    pm_dual<32><<<ntile, 256, 0, stream>>>(H, Mw0, Mb0, Uw0, Ub0, PMT, N);
    edge_fused<<<ntile, 256, 0, stream>>>(PMT, Xe, pair_s, eperm, rowptr,
                                          Mw0 + 32 * HID, Uw0 + 32 * HID, hbuf, N);

    // ---- hidden layers (K1=64) ----
    for (int l = 0; l < 3; l++) {
        const float* Mw = MwH + (size_t)l * 80 * HID;
        const float* Uw = UwH + (size_t)l * 128 * HID;
        pm_dual<64><<<ntile, 256, 0, stream>>>(hbuf, Mw, MbH + (size_t)l * HID,
                                               Uw, UbH + (size_t)l * HID, PMT, N);
        edge_fused<<<ntile, 256, 0, stream>>>(PMT, Xe, pair_s, eperm, rowptr,
                                              Mw + 64 * HID, Uw + 64 * HID, hbuf, N);
    }

    // ---- pooling + head ----
    pool_head<<<256, 256, 0, stream>>>(hbuf, bidx, Ww, Wb, out, N);
}

// Round 5
// 1116.790 us; speedup vs baseline: 4.2992x; 1.1555x over previous
//
#include <hip/hip_runtime.h>
#include <hip/hip_fp16.h>

#define HID 64

struct alignas(8)  H4 { __half2 a, b; };
struct alignas(16) H8 { __half2 a, b, c, d; };

// ===========================================================================
// CSR build: histogram + scan + permutation (+ fp16 edge-feature reorder)
// ===========================================================================
__global__ __launch_bounds__(256) void deg_count(const int* __restrict__ dst,
                                                 int* __restrict__ deg, int E) {
    int e = blockIdx.x * 256 + threadIdx.x;
    if (e < E) atomicAdd(&deg[dst[e]], 1);
}

__global__ __launch_bounds__(256) void scan1(const int* __restrict__ deg,
                                             int* __restrict__ rowptr,
                                             int* __restrict__ bsums, int N) {
    __shared__ int s[256];
    const int t = threadIdx.x;
    const int base = blockIdx.x * 2048 + t * 8;
    int v[8], tot = 0;
    #pragma unroll
    for (int i = 0; i < 8; i++) {
        int x = (base + i < N) ? deg[base + i] : 0;
        v[i] = tot; tot += x;
    }
    s[t] = tot; __syncthreads();
    for (int off = 1; off < 256; off <<= 1) {
        int a = (t >= off) ? s[t - off] : 0;
        __syncthreads(); s[t] += a; __syncthreads();
    }
    const int texcl = s[t] - tot;
    #pragma unroll
    for (int i = 0; i < 8; i++)
        if (base + i < N) rowptr[base + i] = texcl + v[i];
    if (t == 255) bsums[blockIdx.x] = s[255];
}

__global__ void scan2(int* bsums, int NB) {
    if (blockIdx.x == 0 && threadIdx.x == 0) {
        int run = 0;
        for (int i = 0; i < NB; i++) { int x = bsums[i]; bsums[i] = run; run += x; }
    }
}

__global__ __launch_bounds__(256) void scan3(int* __restrict__ rowptr,
                                             const int* __restrict__ bsums,
                                             int N, int E) {
    int idx = blockIdx.x * 256 + threadIdx.x;
    if (idx < N) rowptr[idx] += bsums[idx >> 11];
    if (idx == 0) rowptr[N] = E;
}

__global__ __launch_bounds__(256) void permute_k(
    const int* __restrict__ src, const int* __restrict__ dst,
    const int* __restrict__ rowptr, int* __restrict__ cursor,
    const float* __restrict__ Xe, __half* __restrict__ Xes,
    unsigned* __restrict__ pks, int E)
{
    int e = blockIdx.x * 256 + threadIdx.x;
    if (e >= E) return;
    int d = dst[e];
    int pos = rowptr[d] + atomicAdd(&cursor[d], 1);
    pks[pos] = ((unsigned)src[e] << 5) | (unsigned)(d & 31);
    const float4* xi = (const float4*)&Xe[(size_t)e * 16];
    float4 x0 = xi[0], x1 = xi[1], x2 = xi[2], x3 = xi[3];
    H8 h0, h1;
    h0.a = __float22half2_rn(make_float2(x0.x, x0.y));
    h0.b = __float22half2_rn(make_float2(x0.z, x0.w));
    h0.c = __float22half2_rn(make_float2(x1.x, x1.y));
    h0.d = __float22half2_rn(make_float2(x1.z, x1.w));
    h1.a = __float22half2_rn(make_float2(x2.x, x2.y));
    h1.b = __float22half2_rn(make_float2(x2.z, x2.w));
    h1.c = __float22half2_rn(make_float2(x3.x, x3.y));
    h1.d = __float22half2_rn(make_float2(x3.z, x3.w));
    H8* xo = (H8*)&Xes[(size_t)pos * 16];
    xo[0] = h0; xo[1] = h1;
}

// ===========================================================================
// pm_dual: PMh[n] = fp16(h@Wm_top + bm), Th[n] = fp16(h@Wu_top + bu)
// ===========================================================================
template<int K1>
__global__ __launch_bounds__(256) void pm_dual(
    const float* __restrict__ Hn,   // [N, K1]
    const float* __restrict__ Wm,   // [K1, 64]
    const float* __restrict__ bm,
    const float* __restrict__ Wu,   // [K1, 64]
    const float* __restrict__ bu,
    __half*      __restrict__ PMh,  // [N, 64]
    __half*      __restrict__ Th,   // [N, 64]
    int N)
{
    constexpr int KP = K1 + 4;
    constexpr int P4 = K1 / 4;
    __shared__ float Ws[K1 * 128];
    __shared__ float Xs[32 * KP];

    const int tid = threadIdx.x;
    for (int i = tid; i < K1 * 32; i += 256) {
        const int row = i >> 5, c4 = i & 31;
        float4 v = (c4 < 16) ? *(const float4*)&Wm[row * 64 + c4 * 4]
                             : *(const float4*)&Wu[row * 64 + (c4 - 16) * 4];
        *(float4*)&Ws[row * 128 + c4 * 4] = v;
    }
    const int nbase = blockIdx.x * 32;
    for (int i = tid; i < 32 * P4; i += 256) {
        const int nl = i / P4, part = i % P4;
        const int n = nbase + nl;
        if (n < N)
            *(float4*)&Xs[nl * KP + part * 4] =
                *(const float4*)&Hn[(size_t)n * K1 + part * 4];
    }
    __syncthreads();

    const int c0 = (tid & 31) * 4;
    const int n0 = (tid >> 5) * 4;
    const float4 bv = (c0 < 64) ? *(const float4*)&bm[c0]
                                : *(const float4*)&bu[c0 - 64];

    float4 acc[4];
    #pragma unroll
    for (int i = 0; i < 4; i++) acc[i] = bv;

    #pragma unroll 4
    for (int k = 0; k < K1; k += 4) {
        const float4 w0 = *(const float4*)&Ws[(k + 0) * 128 + c0];
        const float4 w1 = *(const float4*)&Ws[(k + 1) * 128 + c0];
        const float4 w2 = *(const float4*)&Ws[(k + 2) * 128 + c0];
        const float4 w3 = *(const float4*)&Ws[(k + 3) * 128 + c0];
        #pragma unroll
        for (int ni = 0; ni < 4; ni++) {
            const float4 xv = *(const float4*)&Xs[(n0 + ni) * KP + k];
            acc[ni].x += xv.x * w0.x + xv.y * w1.x + xv.z * w2.x + xv.w * w3.x;
            acc[ni].y += xv.x * w0.y + xv.y * w1.y + xv.z * w2.y + xv.w * w3.y;
            acc[ni].z += xv.x * w0.z + xv.y * w1.z + xv.z * w2.z + xv.w * w3.z;
            acc[ni].w += xv.x * w0.w + xv.y * w1.w + xv.z * w2.w + xv.w * w3.w;
        }
    }

    #pragma unroll
    for (int ni = 0; ni < 4; ni++) {
        const int n = nbase + n0 + ni;
        if (n < N) {
            H4 o;
            o.a = __float22half2_rn(make_float2(acc[ni].x, acc[ni].y));
            o.b = __float22half2_rn(make_float2(acc[ni].z, acc[ni].w));
            if (c0 < 64) *(H4*)&PMh[(size_t)n * 64 + c0]      = o;
            else         *(H4*)&Th [(size_t)n * 64 + c0 - 64] = o;
        }
    }
}

// ===========================================================================
// edge_fused: aggs = sum_e relu(PM[src] + Xe@Mw_bot); y = relu(T + aggs@Uw_bot)
// Wave-independent 16-edge chunks; batched gathers; pk double-buffered.
// ===========================================================================
__global__ __launch_bounds__(256) void edge_fused(
    const __half*   __restrict__ PMh,   // [N, 64]
    const __half*   __restrict__ Th,    // [N, 64]
    const __half*   __restrict__ Xes,   // [E, 16] dst-sorted
    const unsigned* __restrict__ pks,   // [E] (src<<5)|ld
    const int*      __restrict__ rowptr,
    const float*    __restrict__ Mwb,   // [16, 64]
    const float*    __restrict__ Uwb,   // [64, 64]
    float*          __restrict__ Yout,  // [N, 64]
    int N)
{
    constexpr int AGP = HID + 4;
    constexpr unsigned NOE = 0xFFFFFFFFu;
    __shared__ float aggs[32 * AGP];    // 8.7 KB
    __shared__ float Xs[4][16 * 20];    // 5.0 KB (per-wave)

    const int tid  = threadIdx.x;
    const int wv   = tid >> 6;
    const int lane = tid & 63;
    const int c0   = (lane & 15) * 4;
    const int g    = lane >> 4;

    float4 wreg[16];
    #pragma unroll
    for (int k = 0; k < 16; k++)
        wreg[k] = *(const float4*)&Mwb[k * 64 + c0];

    for (int i = tid; i < 32 * AGP; i += 256) aggs[i] = 0.f;

    const int nbase  = blockIdx.x * 32;
    const int nend   = (nbase + 32 < N) ? nbase + 32 : N;
    const int estart = rowptr[nbase];
    const int eend   = rowptr[nend];
    __syncthreads();

    float* Xw = Xs[wv];

    int p0 = estart + wv * 16;
    unsigned pkc[4];
    if (p0 < eend) {
        #pragma unroll
        for (int s = 0; s < 4; s++) {
            const int pe = p0 + g * 4 + s;
            pkc[s] = (pe < eend) ? pks[pe] : NOE;
        }
    }

    for (; p0 < eend; p0 += 64) {
        // 1. issue PM gathers (independent, 4 outstanding)
        H4 ph[4];
        #pragma unroll
        for (int s = 0; s < 4; s++)
            if (pkc[s] != NOE)
                ph[s] = *(const H4*)&PMh[(size_t)(pkc[s] >> 5) * 64 + c0];

        // 2. stage Xe tile: 512 B contiguous, convert fp16->fp32 into LDS
        {
            const int el = lane >> 2, part = lane & 3;
            if (p0 + el < eend) {
                H4 xh = *(const H4*)&Xes[(size_t)(p0 + el) * 16 + part * 4];
                float2 lo = __half22float2(xh.a), hi = __half22float2(xh.b);
                *(float4*)&Xw[el * 20 + part * 4] = make_float4(lo.x, lo.y, hi.x, hi.y);
            }
        }

        // 3. prefetch next chunk's pk
        unsigned pkn[4];
        {
            const int p1 = p0 + 64;
            #pragma unroll
            for (int s = 0; s < 4; s++) {
                const int pe = p1 + g * 4 + s;
                pkn[s] = (p1 < eend && pe < eend) ? pks[pe] : NOE;
            }
        }

        // 4. GEMM (acc=0) then add PM, relu, run-merged LDS scatter
        int ld_prev = -1;
        float4 racc = make_float4(0.f, 0.f, 0.f, 0.f);
        #pragma unroll
        for (int s = 0; s < 4; s++) {
            if (pkc[s] != NOE) {
                const float* xr = &Xw[(g * 4 + s) * 20];
                float4 acc = make_float4(0.f, 0.f, 0.f, 0.f);
                #pragma unroll
                for (int k4 = 0; k4 < 4; k4++) {
                    const float4 xv = *(const float4*)&xr[k4 * 4];
                    const float4 w0 = wreg[k4 * 4 + 0];
                    const float4 w1 = wreg[k4 * 4 + 1];
                    const float4 w2 = wreg[k4 * 4 + 2];
                    const float4 w3 = wreg[k4 * 4 + 3];
                    acc.x += xv.x * w0.x + xv.y * w1.x + xv.z * w2.x + xv.w * w3.x;
                    acc.y += xv.x * w0.y + xv.y * w1.y + xv.z * w2.y + xv.w * w3.y;
                    acc.z += xv.x * w0.z + xv.y * w1.z + xv.z * w2.z + xv.w * w3.z;
                    acc.w += xv.x * w0.w + xv.y * w1.w + xv.z * w2.w + xv.w * w3.w;
                }
                const float2 lo = __half22float2(ph[s].a);
                const float2 hi = __half22float2(ph[s].b);
                float4 v;
                v.x = fmaxf(acc.x + lo.x, 0.f);
                v.y = fmaxf(acc.y + lo.y, 0.f);
                v.z = fmaxf(acc.z + hi.x, 0.f);
                v.w = fmaxf(acc.w + hi.y, 0.f);
                const int ld = (int)(pkc[s] & 31u);
                if (ld == ld_prev) {
                    racc.x += v.x; racc.y += v.y; racc.z += v.z; racc.w += v.w;
                } else {
                    if (ld_prev >= 0) {
                        float* a = &aggs[ld_prev * AGP + c0];
                        atomicAdd(a + 0, racc.x); atomicAdd(a + 1, racc.y);
                        atomicAdd(a + 2, racc.z); atomicAdd(a + 3, racc.w);
                    }
                    racc = v; ld_prev = ld;
                }
            }
        }
        if (ld_prev >= 0) {
            float* a = &aggs[ld_prev * AGP + c0];
            atomicAdd(a + 0, racc.x); atomicAdd(a + 1, racc.y);
            atomicAdd(a + 2, racc.z); atomicAdd(a + 3, racc.w);
        }
        pkc[0] = pkn[0]; pkc[1] = pkn[1]; pkc[2] = pkn[2]; pkc[3] = pkn[3];
    }

    __syncthreads();

    // ---- fused node update: y = relu(T + aggs @ Uw_bot), Uwb via L1 ----
    {
        const int c0t = (tid & 15) * 4;
        const int r0  = tid >> 4;
        const int r1  = r0 + 16;
        const int n0g = nbase + r0, n1g = nbase + r1;
        float4 acc0 = make_float4(0.f, 0.f, 0.f, 0.f);
        float4 acc1 = make_float4(0.f, 0.f, 0.f, 0.f);
        if (n0g < N) {
            H4 th = *(const H4*)&Th[(size_t)n0g * 64 + c0t];
            float2 lo = __half22float2(th.a), hi = __half22float2(th.b);
            acc0 = make_float4(lo.x, lo.y, hi.x, hi.y);
        }
        if (n1g < N) {
            H4 th = *(const H4*)&Th[(size_t)n1g * 64 + c0t];
            float2 lo = __half22float2(th.a), hi = __half22float2(th.b);
            acc1 = make_float4(lo.x, lo.y, hi.x, hi.y);
        }
        #pragma unroll 4
        for (int k = 0; k < 64; k += 4) {
            const float4 w0 = *(const float4*)&Uwb[(k + 0) * 64 + c0t];
            const float4 w1 = *(const float4*)&Uwb[(k + 1) * 64 + c0t];
            const float4 w2 = *(const float4*)&Uwb[(k + 2) * 64 + c0t];
            const float4 w3 = *(const float4*)&Uwb[(k + 3) * 64 + c0t];
            const float4 x0 = *(const float4*)&aggs[r0 * AGP + k];
            const float4 x1 = *(const float4*)&aggs[r1 * AGP + k];
            acc0.x += x0.x * w0.x + x0.y * w1.x + x0.z * w2.x + x0.w * w3.x;
            acc0.y += x0.x * w0.y + x0.y * w1.y + x0.z * w2.y + x0.w * w3.y;
            acc0.z += x0.x * w0.z + x0.y * w1.z + x0.z * w2.z + x0.w * w3.z;
            acc0.w += x0.x * w0.w + x0.y * w1.w + x0.z * w2.w + x0.w * w3.w;
            acc1.x += x1.x * w0.x + x1.y * w1.x + x1.z * w2.x + x1.w * w3.x;
            acc1.y += x1.x * w0.y + x1.y * w1.y + x1.z * w2.y + x1.w * w3.y;
            acc1.z += x1.x * w0.z + x1.y * w1.z + x1.z * w2.z + x1.w * w3.z;
            acc1.w += x1.x * w0.w + x1.y * w1.w + x1.z * w2.w + x1.w * w3.w;
        }
        if (n0g < N) {
            float4 o;
            o.x = fmaxf(acc0.x, 0.f); o.y = fmaxf(acc0.y, 0.f);
            o.z = fmaxf(acc0.z, 0.f); o.w = fmaxf(acc0.w, 0.f);
            *(float4*)&Yout[(size_t)n0g * HID + c0t] = o;
        }
        if (n1g < N) {
            float4 o;
            o.x = fmaxf(acc1.x, 0.f); o.y = fmaxf(acc1.y, 0.f);
            o.z = fmaxf(acc1.z, 0.f); o.w = fmaxf(acc1.w, 0.f);
            *(float4*)&Yout[(size_t)n1g * HID + c0t] = o;
        }
    }
}

// ===========================================================================
// pool_head: out[g] = (sum_{n in graph g} y[n]) . Ww + Wb  (sorted batch_idx)
// ===========================================================================
__global__ __launch_bounds__(256) void pool_head(
    const float* __restrict__ Y, const int* __restrict__ bidx,
    const float* __restrict__ Ww, const float* __restrict__ Wb,
    float* __restrict__ out, int N)
{
    const int g = blockIdx.x;
    int a = 0, b = N;
    while (a < b) { int m = (a + b) >> 1; if (bidx[m] < g) a = m + 1; else b = m; }
    const int lo = a;
    b = N;
    while (a < b) { int m = (a + b) >> 1; if (bidx[m] < g + 1) a = m + 1; else b = m; }
    const int hi = a;

    const int tid = threadIdx.x;
    const int c4 = tid & 15, nl = tid >> 4;
    float4 s = make_float4(0.f, 0.f, 0.f, 0.f);
    for (int n = lo + nl; n < hi; n += 16) {
        const float4 v = *(const float4*)&Y[(size_t)n * HID + c4 * 4];
        s.x += v.x; s.y += v.y; s.z += v.z; s.w += v.w;
    }
    __shared__ float red[16 * 68];
    *(float4*)&red[nl * 68 + c4 * 4] = s;
    __syncthreads();
    if (tid < 64) {
        float t = 0.f;
        #pragma unroll
        for (int r = 0; r < 16; r++) t += red[r * 68 + tid];
        t *= Ww[tid];
        #pragma unroll
        for (int off = 32; off; off >>= 1) t += __shfl_down(t, off);
        if (tid == 0) out[g] = t + Wb[0];
    }
}

extern "C" void kernel_launch(void* const* d_in, const int* in_sizes, int n_in,
                              void* d_out, int out_size, void* d_ws, size_t ws_size,
                              hipStream_t stream) {
    const float* H    = (const float*)d_in[0];
    const float* Xe   = (const float*)d_in[1];
    const int*   ids  = (const int*)d_in[2];
    const int*   bidx = (const int*)d_in[3];
    const float* Mw0  = (const float*)d_in[4];
    const float* Mb0  = (const float*)d_in[5];
    const float* Uw0  = (const float*)d_in[6];
    const float* Ub0  = (const float*)d_in[7];
    const float* MwH  = (const float*)d_in[8];   // [3, 80, 64]
    const float* MbH  = (const float*)d_in[9];
    const float* UwH  = (const float*)d_in[10];  // [3, 128, 64]
    const float* UbH  = (const float*)d_in[11];
    const float* Ww   = (const float*)d_in[12];
    const float* Wb   = (const float*)d_in[13];
    float* out = (float*)d_out;

    const int N = in_sizes[0] / 32;
    const int E = in_sizes[1] / 16;
    const int* src = ids;
    const int* dst = ids + E;

    // ---- workspace (≈88 MB) ----
    float*  hbuf = (float*)d_ws;                       // N*64 f32
    __half* PMh  = (__half*)(hbuf + (size_t)N * HID);  // N*64 h
    __half* Th   = PMh + (size_t)N * HID;              // N*64 h
    __half* Xes  = Th  + (size_t)N * HID;              // E*16 h (16B-aligned)
    unsigned* pks = (unsigned*)(Xes + (size_t)E * 16); // E u32
    int* rowptr  = (int*)(pks + E);                    // N+1
    int* deg     = rowptr + (N + 1);                   // N
    int* bsums   = deg + N;                            // <=4096

    const int NB = (N + 2047) / 2048;
    const int eblocks = (E + 255) / 256;
    const int ntile   = (N + 31) / 32;

    // ---- CSR build + fp16 edge reorder ----
    hipMemsetAsync(deg, 0, (size_t)N * sizeof(int), stream);
    deg_count<<<eblocks, 256, 0, stream>>>(dst, deg, E);
    scan1<<<NB, 256, 0, stream>>>(deg, rowptr, bsums, N);
    scan2<<<1, 64, 0, stream>>>(bsums, NB);
    scan3<<<(N + 255) / 256, 256, 0, stream>>>(rowptr, bsums, N, E);
    hipMemsetAsync(deg, 0, (size_t)N * sizeof(int), stream);
    permute_k<<<eblocks, 256, 0, stream>>>(src, dst, rowptr, deg,
                                           Xe, Xes, pks, E);

    // ---- layer 0 (K1=32) ----
    pm_dual<32><<<ntile, 256, 0, stream>>>(H, Mw0, Mb0, Uw0, Ub0, PMh, Th, N);
    edge_fused<<<ntile, 256, 0, stream>>>(PMh, Th, Xes, pks, rowptr,
                                          Mw0 + 32 * HID, Uw0 + 32 * HID, hbuf, N);

    // ---- hidden layers (K1=64) ----
    for (int l = 0; l < 3; l++) {
        const float* Mw = MwH + (size_t)l * 80 * HID;
        const float* Uw = UwH + (size_t)l * 128 * HID;
        pm_dual<64><<<ntile, 256, 0, stream>>>(hbuf, Mw, MbH + (size_t)l * HID,
                                               Uw, UbH + (size_t)l * HID, PMh, Th, N);
        edge_fused<<<ntile, 256, 0, stream>>>(PMh, Th, Xes, pks, rowptr,
                                              Mw + 64 * HID, Uw + 64 * HID, hbuf, N);
    }

    // ---- pooling + head ----
    pool_head<<<256, 256, 0, stream>>>(hbuf, bidx, Ww, Wb, out, N);
}

// Round 6
// 964.775 us; speedup vs baseline: 4.9766x; 1.1576x over previous
//
#include <hip/hip_runtime.h>
#include <hip/hip_fp16.h>

#define HID 64

struct alignas(8)  H4 { __half2 a, b; };
struct alignas(16) H8 { __half2 h[4]; };

typedef _Float16 h2n __attribute__((ext_vector_type(2)));

__device__ inline float dot2f(__half2 a, __half2 b, float c) {
#if __has_builtin(__builtin_amdgcn_fdot2)
    h2n an, bn;
    __builtin_memcpy(&an, &a, 4);
    __builtin_memcpy(&bn, &b, 4);
    return __builtin_amdgcn_fdot2(an, bn, c, false);
#else
    float2 af = __half22float2(a), bf = __half22float2(b);
    return c + af.x * bf.x + af.y * bf.y;
#endif
}

// ===========================================================================
// CSR build: histogram + scan + permutation (+ fp16 edge-feature reorder)
// ===========================================================================
__global__ __launch_bounds__(256) void deg_count(const int* __restrict__ dst,
                                                 int* __restrict__ deg, int E) {
    int e = blockIdx.x * 256 + threadIdx.x;
    if (e < E) atomicAdd(&deg[dst[e]], 1);
}

__global__ __launch_bounds__(256) void scan1(const int* __restrict__ deg,
                                             int* __restrict__ rowptr,
                                             int* __restrict__ bsums, int N) {
    __shared__ int s[256];
    const int t = threadIdx.x;
    const int base = blockIdx.x * 2048 + t * 8;
    int v[8], tot = 0;
    #pragma unroll
    for (int i = 0; i < 8; i++) {
        int x = (base + i < N) ? deg[base + i] : 0;
        v[i] = tot; tot += x;
    }
    s[t] = tot; __syncthreads();
    for (int off = 1; off < 256; off <<= 1) {
        int a = (t >= off) ? s[t - off] : 0;
        __syncthreads(); s[t] += a; __syncthreads();
    }
    const int texcl = s[t] - tot;
    #pragma unroll
    for (int i = 0; i < 8; i++)
        if (base + i < N) rowptr[base + i] = texcl + v[i];
    if (t == 255) bsums[blockIdx.x] = s[255];
}

__global__ void scan2(int* bsums, int NB) {
    if (blockIdx.x == 0 && threadIdx.x == 0) {
        int run = 0;
        for (int i = 0; i < NB; i++) { int x = bsums[i]; bsums[i] = run; run += x; }
    }
}

__global__ __launch_bounds__(256) void scan3(int* __restrict__ rowptr,
                                             const int* __restrict__ bsums,
                                             int N, int E) {
    int idx = blockIdx.x * 256 + threadIdx.x;
    if (idx < N) rowptr[idx] += bsums[idx >> 11];
    if (idx == 0) rowptr[N] = E;
}

__global__ __launch_bounds__(256) void permute_k(
    const int* __restrict__ src, const int* __restrict__ dst,
    const int* __restrict__ rowptr, int* __restrict__ cursor,
    const float* __restrict__ Xe, __half* __restrict__ Xes,
    unsigned* __restrict__ pks, int E)
{
    int e = blockIdx.x * 256 + threadIdx.x;
    if (e >= E) return;
    int d = dst[e];
    int pos = rowptr[d] + atomicAdd(&cursor[d], 1);
    pks[pos] = ((unsigned)src[e] << 5) | (unsigned)(d & 31);
    const float4* xi = (const float4*)&Xe[(size_t)e * 16];
    float4 x0 = xi[0], x1 = xi[1], x2 = xi[2], x3 = xi[3];
    H8 h0, h1;
    h0.h[0] = __float22half2_rn(make_float2(x0.x, x0.y));
    h0.h[1] = __float22half2_rn(make_float2(x0.z, x0.w));
    h0.h[2] = __float22half2_rn(make_float2(x1.x, x1.y));
    h0.h[3] = __float22half2_rn(make_float2(x1.z, x1.w));
    h1.h[0] = __float22half2_rn(make_float2(x2.x, x2.y));
    h1.h[1] = __float22half2_rn(make_float2(x2.z, x2.w));
    h1.h[2] = __float22half2_rn(make_float2(x3.x, x3.y));
    h1.h[3] = __float22half2_rn(make_float2(x3.z, x3.w));
    H8* xo = (H8*)&Xes[(size_t)pos * 16];
    xo[0] = h0; xo[1] = h1;
}

// ===========================================================================
// pm_dual: PMh[n] = fp16(h@Wm_top + bm), Th[n] = fp16(h@Wu_top + bu)
// ===========================================================================
template<int K1>
__global__ __launch_bounds__(256) void pm_dual(
    const float* __restrict__ Hn,
    const float* __restrict__ Wm, const float* __restrict__ bm,
    const float* __restrict__ Wu, const float* __restrict__ bu,
    __half* __restrict__ PMh, __half* __restrict__ Th, int N)
{
    constexpr int KP = K1 + 4;
    constexpr int P4 = K1 / 4;
    __shared__ float Ws[K1 * 128];
    __shared__ float Xs[32 * KP];

    const int tid = threadIdx.x;
    for (int i = tid; i < K1 * 32; i += 256) {
        const int row = i >> 5, c4 = i & 31;
        float4 v = (c4 < 16) ? *(const float4*)&Wm[row * 64 + c4 * 4]
                             : *(const float4*)&Wu[row * 64 + (c4 - 16) * 4];
        *(float4*)&Ws[row * 128 + c4 * 4] = v;
    }
    const int nbase = blockIdx.x * 32;
    for (int i = tid; i < 32 * P4; i += 256) {
        const int nl = i / P4, part = i % P4;
        const int n = nbase + nl;
        if (n < N)
            *(float4*)&Xs[nl * KP + part * 4] =
                *(const float4*)&Hn[(size_t)n * K1 + part * 4];
    }
    __syncthreads();

    const int c0 = (tid & 31) * 4;
    const int n0 = (tid >> 5) * 4;
    const float4 bv = (c0 < 64) ? *(const float4*)&bm[c0]
                                : *(const float4*)&bu[c0 - 64];

    float4 acc[4];
    #pragma unroll
    for (int i = 0; i < 4; i++) acc[i] = bv;

    #pragma unroll 4
    for (int k = 0; k < K1; k += 4) {
        const float4 w0 = *(const float4*)&Ws[(k + 0) * 128 + c0];
        const float4 w1 = *(const float4*)&Ws[(k + 1) * 128 + c0];
        const float4 w2 = *(const float4*)&Ws[(k + 2) * 128 + c0];
        const float4 w3 = *(const float4*)&Ws[(k + 3) * 128 + c0];
        #pragma unroll
        for (int ni = 0; ni < 4; ni++) {
            const float4 xv = *(const float4*)&Xs[(n0 + ni) * KP + k];
            acc[ni].x += xv.x * w0.x + xv.y * w1.x + xv.z * w2.x + xv.w * w3.x;
            acc[ni].y += xv.x * w0.y + xv.y * w1.y + xv.z * w2.y + xv.w * w3.y;
            acc[ni].z += xv.x * w0.z + xv.y * w1.z + xv.z * w2.z + xv.w * w3.z;
            acc[ni].w += xv.x * w0.w + xv.y * w1.w + xv.z * w2.w + xv.w * w3.w;
        }
    }

    #pragma unroll
    for (int ni = 0; ni < 4; ni++) {
        const int n = nbase + n0 + ni;
        if (n < N) {
            H4 o;
            o.a = __float22half2_rn(make_float2(acc[ni].x, acc[ni].y));
            o.b = __float22half2_rn(make_float2(acc[ni].z, acc[ni].w));
            if (c0 < 64) *(H4*)&PMh[(size_t)n * 64 + c0]      = o;
            else         *(H4*)&Th [(size_t)n * 64 + c0 - 64] = o;
        }
    }
}

// ===========================================================================
// edge_fused: aggs = sum_e relu(PM[src] + Xe@Mw_bot); y = relu(T + aggs@Uw_bot)
// 2-deep software pipeline: pk loaded 2 chunks ahead, PM/Xe 1 chunk ahead.
// Xe loaded per-lane direct to VGPRs (contiguous 128 B per lane's 4 edges).
// ===========================================================================
__global__ __launch_bounds__(256) void edge_fused(
    const __half*   __restrict__ PMh,   // [N, 64]
    const __half*   __restrict__ Th,    // [N, 64]
    const __half*   __restrict__ Xes,   // [E, 16] dst-sorted
    const unsigned* __restrict__ pks,   // [E] (src<<5)|ld
    const int*      __restrict__ rowptr,
    const float*    __restrict__ Mwb,   // [16, 64]
    const float*    __restrict__ Uwb,   // [64, 64]
    float*          __restrict__ Yout,  // [N, 64]
    int N)
{
    constexpr int AGP = HID + 4;
    __shared__ float aggs[32 * AGP];    // 8.7 KB (only LDS)

    const int tid  = threadIdx.x;
    const int wv   = tid >> 6;
    const int lane = tid & 63;
    const int c0   = (lane & 15) * 4;
    const int g    = lane >> 4;

    // dot2 weight pairs: wh[p][j] = (Mwb[2p][c0+j], Mwb[2p+1][c0+j])
    __half2 wh[8][4];
    #pragma unroll
    for (int p = 0; p < 8; p++)
        #pragma unroll
        for (int j = 0; j < 4; j++)
            wh[p][j] = __float22half2_rn(make_float2(Mwb[(2 * p) * 64 + c0 + j],
                                                     Mwb[(2 * p + 1) * 64 + c0 + j]));

    for (int i = tid; i < 32 * AGP; i += 256) aggs[i] = 0.f;

    const int nbase  = blockIdx.x * 32;
    const int nend   = (nbase + 32 < N) ? nbase + 32 : N;
    const int estart = rowptr[nbase];
    const int eend   = rowptr[nend];
    __syncthreads();

    int pc = estart + wv * 16;
    unsigned pk_c[4], pk_n[4], pk_n2[4];
    H4 ph_c[4], ph_n[4];
    H8 xh_c[4][2], xh_n[4][2];

    if (pc < eend) {
        // prologue: pk for chunk0 + chunk1, gathers for chunk0
        #pragma unroll
        for (int s = 0; s < 4; s++) {
            const int pe = pc + g * 4 + s;
            pk_c[s] = pks[pe < eend ? pe : eend - 1];
        }
        if (pc + 64 < eend) {
            #pragma unroll
            for (int s = 0; s < 4; s++) {
                const int pe = pc + 64 + g * 4 + s;
                pk_n[s] = pks[pe < eend ? pe : eend - 1];
            }
        }
        #pragma unroll
        for (int s = 0; s < 4; s++) {
            const int pe  = pc + g * 4 + s;
            const int pcl = pe < eend ? pe : eend - 1;
            ph_c[s] = *(const H4*)&PMh[(size_t)(pk_c[s] >> 5) * 64 + c0];
            const H8* xr = (const H8*)&Xes[(size_t)pcl * 16];
            xh_c[s][0] = xr[0]; xh_c[s][1] = xr[1];
        }
    }

    for (; pc < eend; pc += 64) {
        const int pn  = pc + 64;
        const int pn2 = pc + 128;

        // issue gathers for chunk i+1 (pk_n already resident)
        if (pn < eend) {
            #pragma unroll
            for (int s = 0; s < 4; s++) {
                const int pe  = pn + g * 4 + s;
                const int pcl = pe < eend ? pe : eend - 1;
                ph_n[s] = *(const H4*)&PMh[(size_t)(pk_n[s] >> 5) * 64 + c0];
                const H8* xr = (const H8*)&Xes[(size_t)pcl * 16];
                xh_n[s][0] = xr[0]; xh_n[s][1] = xr[1];
            }
        }
        // issue pk for chunk i+2
        if (pn2 < eend) {
            #pragma unroll
            for (int s = 0; s < 4; s++) {
                const int pe = pn2 + g * 4 + s;
                pk_n2[s] = pks[pe < eend ? pe : eend - 1];
            }
        }

        // compute chunk i
        int ld_prev = -1;
        float4 racc = make_float4(0.f, 0.f, 0.f, 0.f);
        #pragma unroll
        for (int s = 0; s < 4; s++) {
            const bool valid = (pc + g * 4 + s) < eend;
            const float2 pl = __half22float2(ph_c[s].a);
            const float2 pu = __half22float2(ph_c[s].b);
            float a0 = pl.x, a1 = pl.y, a2 = pu.x, a3 = pu.y;
            #pragma unroll
            for (int p = 0; p < 8; p++) {
                const __half2 xv = xh_c[s][p >> 2].h[p & 3];
                a0 = dot2f(xv, wh[p][0], a0);
                a1 = dot2f(xv, wh[p][1], a1);
                a2 = dot2f(xv, wh[p][2], a2);
                a3 = dot2f(xv, wh[p][3], a3);
            }
            float4 v;
            v.x = fmaxf(a0, 0.f); v.y = fmaxf(a1, 0.f);
            v.z = fmaxf(a2, 0.f); v.w = fmaxf(a3, 0.f);
            const int ld = valid ? (int)(pk_c[s] & 31u) : -1;
            if (ld == ld_prev) {
                racc.x += v.x; racc.y += v.y; racc.z += v.z; racc.w += v.w;
            } else {
                if (ld_prev >= 0) {
                    float* a = &aggs[ld_prev * AGP + c0];
                    atomicAdd(a + 0, racc.x); atomicAdd(a + 1, racc.y);
                    atomicAdd(a + 2, racc.z); atomicAdd(a + 3, racc.w);
                }
                racc = v; ld_prev = ld;
            }
        }
        if (ld_prev >= 0) {
            float* a = &aggs[ld_prev * AGP + c0];
            atomicAdd(a + 0, racc.x); atomicAdd(a + 1, racc.y);
            atomicAdd(a + 2, racc.z); atomicAdd(a + 3, racc.w);
        }

        // rotate pipeline
        #pragma unroll
        for (int s = 0; s < 4; s++) {
            pk_c[s] = pk_n[s]; pk_n[s] = pk_n2[s];
            ph_c[s] = ph_n[s];
            xh_c[s][0] = xh_n[s][0]; xh_c[s][1] = xh_n[s][1];
        }
    }

    __syncthreads();

    // ---- fused node update: y = relu(T + aggs @ Uw_bot), Uwb via L1 ----
    {
        const int c0t = (tid & 15) * 4;
        const int r0  = tid >> 4;
        const int r1  = r0 + 16;
        const int n0g = nbase + r0, n1g = nbase + r1;
        float4 acc0 = make_float4(0.f, 0.f, 0.f, 0.f);
        float4 acc1 = make_float4(0.f, 0.f, 0.f, 0.f);
        if (n0g < N) {
            H4 th = *(const H4*)&Th[(size_t)n0g * 64 + c0t];
            float2 lo = __half22float2(th.a), hi = __half22float2(th.b);
            acc0 = make_float4(lo.x, lo.y, hi.x, hi.y);
        }
        if (n1g < N) {
            H4 th = *(const H4*)&Th[(size_t)n1g * 64 + c0t];
            float2 lo = __half22float2(th.a), hi = __half22float2(th.b);
            acc1 = make_float4(lo.x, lo.y, hi.x, hi.y);
        }
        #pragma unroll 4
        for (int k = 0; k < 64; k += 4) {
            const float4 w0 = *(const float4*)&Uwb[(k + 0) * 64 + c0t];
            const float4 w1 = *(const float4*)&Uwb[(k + 1) * 64 + c0t];
            const float4 w2 = *(const float4*)&Uwb[(k + 2) * 64 + c0t];
            const float4 w3 = *(const float4*)&Uwb[(k + 3) * 64 + c0t];
            const float4 x0 = *(const float4*)&aggs[r0 * AGP + k];
            const float4 x1 = *(const float4*)&aggs[r1 * AGP + k];
            acc0.x += x0.x * w0.x + x0.y * w1.x + x0.z * w2.x + x0.w * w3.x;
            acc0.y += x0.x * w0.y + x0.y * w1.y + x0.z * w2.y + x0.w * w3.y;
            acc0.z += x0.x * w0.z + x0.y * w1.z + x0.z * w2.z + x0.w * w3.z;
            acc0.w += x0.x * w0.w + x0.y * w1.w + x0.z * w2.w + x0.w * w3.w;
            acc1.x += x1.x * w0.x + x1.y * w1.x + x1.z * w2.x + x1.w * w3.x;
            acc1.y += x1.x * w0.y + x1.y * w1.y + x1.z * w2.y + x1.w * w3.y;
            acc1.z += x1.x * w0.z + x1.y * w1.z + x1.z * w2.z + x1.w * w3.z;
            acc1.w += x1.x * w0.w + x1.y * w1.w + x1.z * w2.w + x1.w * w3.w;
        }
        if (n0g < N) {
            float4 o;
            o.x = fmaxf(acc0.x, 0.f); o.y = fmaxf(acc0.y, 0.f);
            o.z = fmaxf(acc0.z, 0.f); o.w = fmaxf(acc0.w, 0.f);
            *(float4*)&Yout[(size_t)n0g * HID + c0t] = o;
        }
        if (n1g < N) {
            float4 o;
            o.x = fmaxf(acc1.x, 0.f); o.y = fmaxf(acc1.y, 0.f);
            o.z = fmaxf(acc1.z, 0.f); o.w = fmaxf(acc1.w, 0.f);
            *(float4*)&Yout[(size_t)n1g * HID + c0t] = o;
        }
    }
}

// ===========================================================================
// pool_head: out[g] = (sum_{n in graph g} y[n]) . Ww + Wb  (sorted batch_idx)
// ===========================================================================
__global__ __launch_bounds__(256) void pool_head(
    const float* __restrict__ Y, const int* __restrict__ bidx,
    const float* __restrict__ Ww, const float* __restrict__ Wb,
    float* __restrict__ out, int N)
{
    const int g = blockIdx.x;
    int a = 0, b = N;
    while (a < b) { int m = (a + b) >> 1; if (bidx[m] < g) a = m + 1; else b = m; }
    const int lo = a;
    b = N;
    while (a < b) { int m = (a + b) >> 1; if (bidx[m] < g + 1) a = m + 1; else b = m; }
    const int hi = a;

    const int tid = threadIdx.x;
    const int c4 = tid & 15, nl = tid >> 4;
    float4 s = make_float4(0.f, 0.f, 0.f, 0.f);
    for (int n = lo + nl; n < hi; n += 16) {
        const float4 v = *(const float4*)&Y[(size_t)n * HID + c4 * 4];
        s.x += v.x; s.y += v.y; s.z += v.z; s.w += v.w;
    }
    __shared__ float red[16 * 68];
    *(float4*)&red[nl * 68 + c4 * 4] = s;
    __syncthreads();
    if (tid < 64) {
        float t = 0.f;
        #pragma unroll
        for (int r = 0; r < 16; r++) t += red[r * 68 + tid];
        t *= Ww[tid];
        #pragma unroll
        for (int off = 32; off; off >>= 1) t += __shfl_down(t, off);
        if (tid == 0) out[g] = t + Wb[0];
    }
}

extern "C" void kernel_launch(void* const* d_in, const int* in_sizes, int n_in,
                              void* d_out, int out_size, void* d_ws, size_t ws_size,
                              hipStream_t stream) {
    const float* H    = (const float*)d_in[0];
    const float* Xe   = (const float*)d_in[1];
    const int*   ids  = (const int*)d_in[2];
    const int*   bidx = (const int*)d_in[3];
    const float* Mw0  = (const float*)d_in[4];
    const float* Mb0  = (const float*)d_in[5];
    const float* Uw0  = (const float*)d_in[6];
    const float* Ub0  = (const float*)d_in[7];
    const float* MwH  = (const float*)d_in[8];   // [3, 80, 64]
    const float* MbH  = (const float*)d_in[9];
    const float* UwH  = (const float*)d_in[10];  // [3, 128, 64]
    const float* UbH  = (const float*)d_in[11];
    const float* Ww   = (const float*)d_in[12];
    const float* Wb   = (const float*)d_in[13];
    float* out = (float*)d_out;

    const int N = in_sizes[0] / 32;
    const int E = in_sizes[1] / 16;
    const int* src = ids;
    const int* dst = ids + E;

    // ---- workspace ----
    float*  hbuf = (float*)d_ws;                       // N*64 f32
    __half* PMh  = (__half*)(hbuf + (size_t)N * HID);  // N*64 h
    __half* Th   = PMh + (size_t)N * HID;              // N*64 h
    __half* Xes  = Th  + (size_t)N * HID;              // E*16 h
    unsigned* pks = (unsigned*)(Xes + (size_t)E * 16); // E u32
    int* rowptr  = (int*)(pks + E);                    // N+1
    int* deg     = rowptr + (N + 1);                   // N
    int* bsums   = deg + N;                            // <=4096

    const int NB = (N + 2047) / 2048;
    const int eblocks = (E + 255) / 256;
    const int ntile   = (N + 31) / 32;

    // ---- CSR build + fp16 edge reorder ----
    hipMemsetAsync(deg, 0, (size_t)N * sizeof(int), stream);
    deg_count<<<eblocks, 256, 0, stream>>>(dst, deg, E);
    scan1<<<NB, 256, 0, stream>>>(deg, rowptr, bsums, N);
    scan2<<<1, 64, 0, stream>>>(bsums, NB);
    scan3<<<(N + 255) / 256, 256, 0, stream>>>(rowptr, bsums, N, E);
    hipMemsetAsync(deg, 0, (size_t)N * sizeof(int), stream);
    permute_k<<<eblocks, 256, 0, stream>>>(src, dst, rowptr, deg,
                                           Xe, Xes, pks, E);

    // ---- layer 0 (K1=32) ----
    pm_dual<32><<<ntile, 256, 0, stream>>>(H, Mw0, Mb0, Uw0, Ub0, PMh, Th, N);
    edge_fused<<<ntile, 256, 0, stream>>>(PMh, Th, Xes, pks, rowptr,
                                          Mw0 + 32 * HID, Uw0 + 32 * HID, hbuf, N);

    // ---- hidden layers (K1=64) ----
    for (int l = 0; l < 3; l++) {
        const float* Mw = MwH + (size_t)l * 80 * HID;
        const float* Uw = UwH + (size_t)l * 128 * HID;
        pm_dual<64><<<ntile, 256, 0, stream>>>(hbuf, Mw, MbH + (size_t)l * HID,
                                               Uw, UbH + (size_t)l * HID, PMh, Th, N);
        edge_fused<<<ntile, 256, 0, stream>>>(PMh, Th, Xes, pks, rowptr,
                                              Mw + 64 * HID, Uw + 64 * HID, hbuf, N);
    }

    // ---- pooling + head ----
    pool_head<<<256, 256, 0, stream>>>(hbuf, bidx, Ww, Wb, out, N);
}